// Round 6
// baseline (1567.043 us; speedup 1.0000x reference)
//
#include <hip/hip_runtime.h>
#include <cmath>

#define D_MODEL 512
#define T_TOK   4096
#define S_SEQ   1024
#define DH_FF   2048
#define N_EXP   8
#define CAP     9216    // 8192 assignments + 8*127 pad, 128-aligned
#define QKV_LD  1536

typedef __attribute__((ext_vector_type(8))) short bf16x8_t;
typedef __attribute__((ext_vector_type(4))) float f32x4_t;
typedef _Float16 f16x8 __attribute__((ext_vector_type(8)));

__device__ __forceinline__ float gelu_exact(float x) {
    return 0.5f * x * (1.0f + erff(x * 0.70710678118654752440f));
}
__device__ __forceinline__ unsigned short f2bf(float f) {
    union { float f; unsigned int u; } v; v.f = f;
    unsigned int r = v.u + 0x7fff + ((v.u >> 16) & 1);   // RNE
    return (unsigned short)(r >> 16);
}
__device__ __forceinline__ float bf2f(unsigned short u) {
    union { unsigned int i; float f; } v; v.i = ((unsigned int)u) << 16; return v.f;
}
__device__ __forceinline__ unsigned short f2h(float f) {
    _Float16 h = (_Float16)f;
    return __builtin_bit_cast(unsigned short, h);
}
// fp32 -> fp16 hi + fp16 lo (Ootomo split): v ~= hi + lo, rel err ~2^-22
__device__ __forceinline__ void split1(float v, unsigned short& h, unsigned short& l) {
    _Float16 hf = (_Float16)v;
    _Float16 lf = (_Float16)(v - (float)hf);
    h = __builtin_bit_cast(unsigned short, hf);
    l = __builtin_bit_cast(unsigned short, lf);
}

// ---------------- LayerNorm: fp32 in -> optional {fp32, fp16 hi/lo, bf16, xcopy} ----------------
__global__ __launch_bounds__(256) void ln_kernel(
    const float* __restrict__ x, const float* __restrict__ w,
    const float* __restrict__ b, float* __restrict__ outf,
    unsigned short* __restrict__ outHi, unsigned short* __restrict__ outLo,
    unsigned short* __restrict__ outb, float* __restrict__ xcopy)
{
    const int t = blockIdx.x, tid = threadIdx.x;
    const float* xr = x + (size_t)t * D_MODEL;
    float v0 = xr[tid], v1 = xr[tid + 256];
    __shared__ float ss[256], sq[256];
    ss[tid] = v0 + v1;
    sq[tid] = v0 * v0 + v1 * v1;
    __syncthreads();
    for (int st = 128; st > 0; st >>= 1) {
        if (tid < st) { ss[tid] += ss[tid + st]; sq[tid] += sq[tid + st]; }
        __syncthreads();
    }
    float mu  = ss[0] * (1.0f / 512.0f);
    float var = sq[0] * (1.0f / 512.0f) - mu * mu;
    float rs  = rsqrtf(var + 1e-6f);
    float o0 = (v0 - mu) * rs * w[tid]       + b[tid];
    float o1 = (v1 - mu) * rs * w[tid + 256] + b[tid + 256];
    if (outf) {
        float* outr = outf + (size_t)t * D_MODEL;
        outr[tid] = o0; outr[tid + 256] = o1;
    }
    if (outHi) {
        unsigned short h0, l0, h1, l1;
        split1(o0, h0, l0); split1(o1, h1, l1);
        unsigned short* oh = outHi + (size_t)t * D_MODEL;
        unsigned short* ol = outLo + (size_t)t * D_MODEL;
        oh[tid] = h0; oh[tid + 256] = h1;
        ol[tid] = l0; ol[tid + 256] = l1;
    }
    if (outb) {
        unsigned short* ob = outb + (size_t)t * D_MODEL;
        ob[tid] = f2bf(o0); ob[tid + 256] = f2bf(o1);
    }
    if (xcopy) {
        float* xc = xcopy + (size_t)t * D_MODEL;
        xc[tid] = v0; xc[tid + 256] = v1;
    }
}

// ------- Transpose-split: fp32 [K,N] slab -> fp16 hi[N,K] + lo[N,K] (wide grid) -------
__global__ __launch_bounds__(256) void tconv_split(
    const float* __restrict__ in, int inLd, size_t eStrideIn,
    unsigned short* __restrict__ outHi, unsigned short* __restrict__ outLo,
    int outLd, size_t eStrideOut)
{
    __shared__ float Ts[32][33];
    const int tid = threadIdx.x;
    const int k0 = blockIdx.y * 32, n0 = blockIdx.x * 32;
    in    += (size_t)blockIdx.z * eStrideIn;
    outHi += (size_t)blockIdx.z * eStrideOut;
    outLo += (size_t)blockIdx.z * eStrideOut;
    int r = tid >> 3, c = (tid & 7) * 4;
    float4 v = *(const float4*)&in[(size_t)(k0 + r) * inLd + n0 + c];
    Ts[r][c] = v.x; Ts[r][c + 1] = v.y; Ts[r][c + 2] = v.z; Ts[r][c + 3] = v.w;
    __syncthreads();
    int n = tid >> 3, kk = (tid & 7) * 4;
    ushort4 h4, l4;
    split1(Ts[kk][n],     h4.x, l4.x); split1(Ts[kk + 1][n], h4.y, l4.y);
    split1(Ts[kk + 2][n], h4.z, l4.z); split1(Ts[kk + 3][n], h4.w, l4.w);
    size_t o = (size_t)(n0 + n) * outLd + k0 + kk;
    *(ushort4*)&outHi[o] = h4;
    *(ushort4*)&outLo[o] = l4;
}

// ------- Transpose-convert bf16 (L2 MoE weights, wide grid) -------
__global__ __launch_bounds__(256) void tconv(
    const float* __restrict__ in, int inLd, size_t eStrideIn,
    unsigned short* __restrict__ out, int outLd, size_t eStrideOut)
{
    __shared__ float Ts[32][33];
    const int tid = threadIdx.x;
    const int k0 = blockIdx.y * 32, n0 = blockIdx.x * 32;
    in  += (size_t)blockIdx.z * eStrideIn;
    out += (size_t)blockIdx.z * eStrideOut;
    int r = tid >> 3, c = (tid & 7) * 4;
    float4 v = *(const float4*)&in[(size_t)(k0 + r) * inLd + n0 + c];
    Ts[r][c] = v.x; Ts[r][c + 1] = v.y; Ts[r][c + 2] = v.z; Ts[r][c + 3] = v.w;
    __syncthreads();
    int n = tid >> 3, kk = (tid & 7) * 4;
    ushort4 o;
    o.x = f2bf(Ts[kk][n]);     o.y = f2bf(Ts[kk + 1][n]);
    o.z = f2bf(Ts[kk + 2][n]); o.w = f2bf(Ts[kk + 3][n]);
    *(ushort4*)&out[(size_t)(n0 + n) * outLd + k0 + kk] = o;
}

// ================= fp16x3 MFMA GEMM, BM=128 x BN tiles, K-step 32, reg-prefetch =========
// A pre-split hi/lo [M][K] (MODE2: gathered rows); B pre-split hi/lo [N][K] K-contig.
// MODE 0: C fp32 = acc                 (qkv)
// MODE 1: C fp32 = acc + bias + resid  (o proj)
// MODE 2: Chi/Clo = split(gelu(acc+bias_e)), A gathered via rowtok (MoE up)
// MODE 5: atomicAdd(C[tok], rowgate*(acc + beta?bias_e:0)), skip pads (MoE down; rowgate via resid)
template<int MODE, int BN>
__global__ __launch_bounds__(256) void gemm128(
    const unsigned short* __restrict__ Ahi, const unsigned short* __restrict__ Alo,
    int lda, int KLEN,
    const unsigned short* __restrict__ Bhi, const unsigned short* __restrict__ Blo,
    size_t BeStride,
    float* __restrict__ C, int ldc,
    const float* __restrict__ bias, int biasStride,
    const float* __restrict__ resid,
    const int* __restrict__ offs, const int* __restrict__ rowtok, int beta,
    unsigned short* __restrict__ Chi, unsigned short* __restrict__ Clo)
{
    constexpr int NI  = (BN == 64) ? 2 : 4;   // A-frags per wave
    constexpr int NBV = BN / 64;              // B staging vecs per thread per array
    __shared__ unsigned short AsH[128][40], AsL[128][40];
    __shared__ unsigned short BsH[BN][40],  BsL[BN][40];
    __shared__ int rt[128];
    __shared__ float rg[128];
    const int tid = threadIdx.x;
    const int row0 = blockIdx.y * 128, col0 = blockIdx.x * BN;
    int e = 0;
    if (MODE == 2 || MODE == 5) {
        #pragma unroll
        for (int i = 1; i < N_EXP; i++) if (offs[i] <= row0) e = i;
        if (tid < 128) rt[tid] = rowtok[row0 + tid];
        else if (MODE == 5) rg[tid - 128] = resid[row0 + tid - 128];
        __syncthreads();
    }
    const unsigned short* BeH = Bhi + (size_t)e * BeStride;
    const unsigned short* BeL = Blo + (size_t)e * BeStride;
    const int lane = tid & 63, w = tid >> 6;
    const int wrow = (BN == 64) ? w * 32 : (w >> 1) * 64;
    const int wcol = (BN == 64) ? 0 : (w & 1) * 64;
    const int m_ = lane & 15, q_ = lane >> 4;
    f32x4_t acc[NI][4];
    #pragma unroll
    for (int i = 0; i < NI; i++)
        #pragma unroll
        for (int j = 0; j < 4; j++) acc[i][j] = (f32x4_t){0.f, 0.f, 0.f, 0.f};

    // staging mapping: vec v covers row (v>>2), shorts (v&3)*8..+7
    const int ar0 = tid >> 2, ac = (tid & 3) * 8;
    size_t aoff[2]; bool az[2];
    #pragma unroll
    for (int q = 0; q < 2; q++) {
        int r = q * 64 + ar0;
        if (MODE == 2) {
            int t = rt[r];
            az[q] = (t < 0);
            aoff[q] = (size_t)(az[q] ? 0 : t) * lda;
        } else { az[q] = false; aoff[q] = (size_t)(row0 + r) * lda; }
    }
    size_t boff[NBV];
    #pragma unroll
    for (int q = 0; q < NBV; q++)
        boff[q] = (size_t)(col0 + q * 64 + ar0) * KLEN;

    const uint4 Z = make_uint4(0u, 0u, 0u, 0u);
    uint4 pah[2], pal[2], pbh[NBV], pbl[NBV];
    auto LOAD = [&](int k0) {
        #pragma unroll
        for (int q = 0; q < 2; q++) {
            pah[q] = az[q] ? Z : *(const uint4*)&Ahi[aoff[q] + k0 + ac];
            pal[q] = az[q] ? Z : *(const uint4*)&Alo[aoff[q] + k0 + ac];
        }
        #pragma unroll
        for (int q = 0; q < NBV; q++) {
            pbh[q] = *(const uint4*)&BeH[boff[q] + k0 + ac];
            pbl[q] = *(const uint4*)&BeL[boff[q] + k0 + ac];
        }
    };
    auto STORE = [&]() {
        #pragma unroll
        for (int q = 0; q < 2; q++) {
            *(uint4*)&AsH[q * 64 + ar0][ac] = pah[q];
            *(uint4*)&AsL[q * 64 + ar0][ac] = pal[q];
        }
        #pragma unroll
        for (int q = 0; q < NBV; q++) {
            *(uint4*)&BsH[q * 64 + ar0][ac] = pbh[q];
            *(uint4*)&BsL[q * 64 + ar0][ac] = pbl[q];
        }
    };

    const int NS = KLEN / 32;
    LOAD(0);
    for (int ks = 0; ks < NS; ks++) {
        if (ks) __syncthreads();
        STORE();
        if (ks + 1 < NS) LOAD(32 * (ks + 1));   // in flight during compute
        __syncthreads();
        f16x8 ah[NI], al[NI];
        #pragma unroll
        for (int i = 0; i < NI; i++) {
            int r = wrow + 16 * i + m_;
            ah[i] = *(const f16x8*)&AsH[r][q_ * 8];
            al[i] = *(const f16x8*)&AsL[r][q_ * 8];
        }
        #pragma unroll
        for (int j = 0; j < 4; j++) {
            int r = wcol + 16 * j + m_;
            f16x8 bh = *(const f16x8*)&BsH[r][q_ * 8];
            f16x8 bl = *(const f16x8*)&BsL[r][q_ * 8];
            #pragma unroll
            for (int i = 0; i < NI; i++) {
                acc[i][j] = __builtin_amdgcn_mfma_f32_16x16x32_f16(ah[i], bl, acc[i][j], 0, 0, 0);
                acc[i][j] = __builtin_amdgcn_mfma_f32_16x16x32_f16(al[i], bh, acc[i][j], 0, 0, 0);
                acc[i][j] = __builtin_amdgcn_mfma_f32_16x16x32_f16(ah[i], bh, acc[i][j], 0, 0, 0);
            }
        }
    }
    // C/D layout: col = lane&15, row = (lane>>4)*4 + reg  [validated r4]
    #pragma unroll
    for (int i = 0; i < NI; i++) {
        #pragma unroll
        for (int j = 0; j < 4; j++) {
            #pragma unroll
            for (int r = 0; r < 4; r++) {
                int lr = wrow + 16 * i + q_ * 4 + r;
                int gr = row0 + lr;
                int gc = col0 + wcol + 16 * j + m_;
                float v = acc[i][j][r];
                if (MODE == 5) {
                    int t = rt[lr];
                    if (t >= 0) {
                        float add = beta ? bias[(size_t)e * biasStride + gc] : 0.0f;
                        atomicAdd(&C[(size_t)t * ldc + gc], rg[lr] * (v + add));
                    }
                } else if (MODE == 2) {
                    float g = gelu_exact(v + bias[(size_t)e * biasStride + gc]);
                    unsigned short gh, gl;
                    split1(g, gh, gl);
                    size_t idx = (size_t)gr * ldc + gc;
                    Chi[idx] = gh; Clo[idx] = gl;
                } else {
                    size_t idx = (size_t)gr * ldc + gc;
                    if (MODE == 1) C[idx] = v + bias[gc] + resid[idx];
                    else           C[idx] = v;
                }
            }
        }
    }
}

// ================= bf16 MFMA GEMM (L2 MoE), BM=128 x BN, K-step 64, reg-prefetch =========
// MODE 2: C bf16 = gelu(acc+bias_e), A bf16 gathered via rowtok (MoE up)
// MODE 5: atomicAdd(Cout[tok], rowgate*(acc + beta?bias_e:0)), skip pads
template<int MODE, int BN>
__global__ __launch_bounds__(256) void gemm128_bt(
    const unsigned short* __restrict__ A, int lda, int KLEN,
    const unsigned short* __restrict__ Bt, size_t BeStride,
    unsigned short* __restrict__ C, int ldc,
    const float* __restrict__ biasBase, int biasStride,
    const int* __restrict__ offs, const int* __restrict__ rowtok,
    const float* __restrict__ rowgate, float* __restrict__ Cout, int beta)
{
    constexpr int NI  = (BN == 64) ? 2 : 4;
    constexpr int NBV = BN / 32;
    __shared__ unsigned short As[128][72];
    __shared__ unsigned short Bs[BN][72];
    __shared__ int rt[128];
    __shared__ float rg[128];
    const int tid = threadIdx.x;
    const int row0 = blockIdx.y * 128, col0 = blockIdx.x * BN;
    int e = 0;
    #pragma unroll
    for (int i = 1; i < N_EXP; i++) if (offs[i] <= row0) e = i;
    if (tid < 128) rt[tid] = rowtok[row0 + tid];
    else if (MODE == 5) rg[tid - 128] = rowgate[row0 + tid - 128];
    __syncthreads();
    const unsigned short* Be = Bt + (size_t)e * BeStride;
    const int lane = tid & 63, w = tid >> 6;
    const int wrow = (BN == 64) ? w * 32 : (w >> 1) * 64;
    const int wcol = (BN == 64) ? 0 : (w & 1) * 64;
    const int m_ = lane & 15, q_ = lane >> 4;
    f32x4_t acc[NI][4];
    #pragma unroll
    for (int i = 0; i < NI; i++)
        #pragma unroll
        for (int j = 0; j < 4; j++) acc[i][j] = (f32x4_t){0.f, 0.f, 0.f, 0.f};

    // staging: vec v covers row (v>>3), shorts (v&7)*8..+7 (K-step 64)
    const int ar0 = tid >> 3, ac = (tid & 7) * 8;
    size_t aoff[4]; bool az[4];
    #pragma unroll
    for (int q = 0; q < 4; q++) {
        int r = q * 32 + ar0;
        if (MODE == 2) {
            int t = rt[r];
            az[q] = (t < 0);
            aoff[q] = (size_t)(az[q] ? 0 : t) * lda;
        } else { az[q] = false; aoff[q] = (size_t)(row0 + r) * lda; }
    }
    size_t boff[NBV];
    #pragma unroll
    for (int q = 0; q < NBV; q++)
        boff[q] = (size_t)(col0 + q * 32 + ar0) * KLEN;

    const uint4 Z = make_uint4(0u, 0u, 0u, 0u);
    uint4 pa[4], pb[NBV];
    auto LOAD = [&](int k0) {
        #pragma unroll
        for (int q = 0; q < 4; q++)
            pa[q] = az[q] ? Z : *(const uint4*)&A[aoff[q] + k0 + ac];
        #pragma unroll
        for (int q = 0; q < NBV; q++)
            pb[q] = *(const uint4*)&Be[boff[q] + k0 + ac];
    };
    auto STORE = [&]() {
        #pragma unroll
        for (int q = 0; q < 4; q++)
            *(uint4*)&As[q * 32 + ar0][ac] = pa[q];
        #pragma unroll
        for (int q = 0; q < NBV; q++)
            *(uint4*)&Bs[q * 32 + ar0][ac] = pb[q];
    };

    const int NS = KLEN / 64;
    LOAD(0);
    for (int ks = 0; ks < NS; ks++) {
        if (ks) __syncthreads();
        STORE();
        if (ks + 1 < NS) LOAD(64 * (ks + 1));
        __syncthreads();
        #pragma unroll
        for (int ks2 = 0; ks2 < 2; ks2++) {
            bf16x8_t af[NI];
            #pragma unroll
            for (int i = 0; i < NI; i++)
                af[i] = *(const bf16x8_t*)&As[wrow + 16 * i + m_][ks2 * 32 + q_ * 8];
            #pragma unroll
            for (int j = 0; j < 4; j++) {
                bf16x8_t bfr = *(const bf16x8_t*)&Bs[wcol + 16 * j + m_][ks2 * 32 + q_ * 8];
                #pragma unroll
                for (int i = 0; i < NI; i++)
                    acc[i][j] = __builtin_amdgcn_mfma_f32_16x16x32_bf16(
                        af[i], bfr, acc[i][j], 0, 0, 0);
            }
        }
    }
    #pragma unroll
    for (int i = 0; i < NI; i++) {
        #pragma unroll
        for (int j = 0; j < 4; j++) {
            #pragma unroll
            for (int r = 0; r < 4; r++) {
                int lr = wrow + 16 * i + q_ * 4 + r;
                int gr = row0 + lr;
                int gc = col0 + wcol + 16 * j + m_;
                float v = acc[i][j][r];
                if (MODE == 5) {
                    int t = rt[lr];
                    if (t >= 0) {
                        float add = beta ? biasBase[(size_t)e * biasStride + gc] : 0.0f;
                        atomicAdd(&Cout[(size_t)t * ldc + gc], rg[lr] * (v + add));
                    }
                } else {
                    C[(size_t)gr * ldc + gc] =
                        f2bf(gelu_exact(v + biasBase[(size_t)e * biasStride + gc]));
                }
            }
        }
    }
}

// ---------------- QKV prep: fp32 qkvb slab -> fp16 head-major Q (x0.125), K, V^T ----------------
__global__ __launch_bounds__(256) void qkv_prep(
    const float* __restrict__ qkvb, unsigned short* __restrict__ Qh,
    unsigned short* __restrict__ Kh, unsigned short* __restrict__ VTh)
{
    __shared__ float Ts[64][65];
    const int tid = threadIdx.x;
    const int t0 = blockIdx.x * 64, hh = blockIdx.y, b = blockIdx.z;
    const int bh = b * 8 + hh;
    const float* src = qkvb + ((size_t)(b * S_SEQ + t0)) * QKV_LD + hh * 64;
    #pragma unroll
    for (int i = 0; i < 4; i++) {
        int flat = tid + i * 256;
        int r = flat >> 4, c4 = (flat & 15) * 4;
        float4 qv = *(const float4*)&src[(size_t)r * QKV_LD + c4];
        float4 kv = *(const float4*)&src[(size_t)r * QKV_LD + 512 + c4];
        float4 vv = *(const float4*)&src[(size_t)r * QKV_LD + 1024 + c4];
        ushort4 qo, ko;
        qo.x = f2h(qv.x * 0.125f); qo.y = f2h(qv.y * 0.125f);
        qo.z = f2h(qv.z * 0.125f); qo.w = f2h(qv.w * 0.125f);
        ko.x = f2h(kv.x); ko.y = f2h(kv.y); ko.z = f2h(kv.z); ko.w = f2h(kv.w);
        size_t o = ((size_t)bh * S_SEQ + t0 + r) * 64 + c4;
        *(ushort4*)&Qh[o] = qo;
        *(ushort4*)&Kh[o] = ko;
        Ts[r][c4] = vv.x; Ts[r][c4 + 1] = vv.y; Ts[r][c4 + 2] = vv.z; Ts[r][c4 + 3] = vv.w;
    }
    __syncthreads();
    #pragma unroll
    for (int i = 0; i < 4; i++) {
        int flat = tid + i * 256;
        int d = flat >> 4, s4 = (flat & 15) * 4;
        ushort4 vo;
        vo.x = f2h(Ts[s4][d]);     vo.y = f2h(Ts[s4 + 1][d]);
        vo.z = f2h(Ts[s4 + 2][d]); vo.w = f2h(Ts[s4 + 3][d]);
        *(ushort4*)&VTh[((size_t)bh * 64 + d) * S_SEQ + t0 + s4] = vo;
    }
}

// ---------------- Flash attention, fp16 MFMA; epilogue emits hi/lo split ----------------
__global__ __launch_bounds__(256) void flash_attn_mfma(
    const unsigned short* __restrict__ Qh, const unsigned short* __restrict__ Kh,
    const unsigned short* __restrict__ VTh,
    unsigned short* __restrict__ outHi, unsigned short* __restrict__ outLo)
{
    __shared__ unsigned short Ks[64 * 72];
    __shared__ unsigned short Vt[64 * 72];
    __shared__ unsigned short Ps[64 * 72];
    const int tid = threadIdx.x;
    const int lane = tid & 63, w = tid >> 6;
    const int m_ = lane & 15, q_ = lane >> 4;
    const int hh = blockIdx.y, b = blockIdx.z;
    const int bh = b * 8 + hh;
    const int q0 = blockIdx.x * 64;
    const size_t qbase = ((size_t)bh * S_SEQ + q0) * 64;
    const size_t kbase = (size_t)bh * S_SEQ * 64;
    const size_t vbase = (size_t)bh * 64 * S_SEQ;

    f16x8 qa[2];
    #pragma unroll
    for (int c = 0; c < 2; c++)
        qa[c] = *(const f16x8*)&Qh[qbase + (size_t)(w * 16 + m_) * 64 + c * 32 + q_ * 8];

    float m_run[4], l_run[4];
    f32x4_t acc[4];
    #pragma unroll
    for (int r = 0; r < 4; r++) { m_run[r] = -INFINITY; l_run[r] = 0.0f; }
    #pragma unroll
    for (int oj = 0; oj < 4; oj++) acc[oj] = (f32x4_t){0.f, 0.f, 0.f, 0.f};

    for (int kv0 = 0; kv0 < S_SEQ; kv0 += 64) {
        __syncthreads();
        #pragma unroll
        for (int i = 0; i < 2; i++) {
            int g = tid + i * 256;
            int r = g >> 3, c8 = (g & 7) * 8;
            *(uint4*)&Ks[r * 72 + c8] =
                *(const uint4*)&Kh[kbase + (size_t)(kv0 + r) * 64 + c8];
            *(uint4*)&Vt[r * 72 + c8] =
                *(const uint4*)&VTh[vbase + (size_t)r * S_SEQ + kv0 + c8];
        }
        __syncthreads();
        f32x4_t s[4];
        #pragma unroll
        for (int j = 0; j < 4; j++) s[j] = (f32x4_t){0.f, 0.f, 0.f, 0.f};
        #pragma unroll
        for (int c = 0; c < 2; c++)
            #pragma unroll
            for (int j = 0; j < 4; j++) {
                f16x8 kb = *(const f16x8*)&Ks[(j * 16 + m_) * 72 + c * 32 + q_ * 8];
                s[j] = __builtin_amdgcn_mfma_f32_16x16x32_f16(qa[c], kb, s[j], 0, 0, 0);
            }
        float alpha[4];
        #pragma unroll
        for (int r = 0; r < 4; r++) {
            float rm = fmaxf(fmaxf(s[0][r], s[1][r]), fmaxf(s[2][r], s[3][r]));
            #pragma unroll
            for (int mk = 1; mk < 16; mk <<= 1)
                rm = fmaxf(rm, __shfl_xor(rm, mk));
            float mn = fmaxf(m_run[r], rm);
            alpha[r] = __expf(m_run[r] - mn);
            m_run[r] = mn;
            float ps = 0.0f;
            #pragma unroll
            for (int j = 0; j < 4; j++) {
                float p = __expf(s[j][r] - mn);
                s[j][r] = p;
                ps += p;
            }
            #pragma unroll
            for (int mk = 1; mk < 16; mk <<= 1)
                ps += __shfl_xor(ps, mk);
            l_run[r] = l_run[r] * alpha[r] + ps;
        }
        #pragma unroll
        for (int oj = 0; oj < 4; oj++)
            #pragma unroll
            for (int r = 0; r < 4; r++)
                acc[oj][r] *= alpha[r];
        #pragma unroll
        for (int j = 0; j < 4; j++)
            #pragma unroll
            for (int r = 0; r < 4; r++)
                Ps[(w * 16 + q_ * 4 + r) * 72 + j * 16 + m_] = f2h(s[j][r]);
        __syncthreads();
        #pragma unroll
        for (int c = 0; c < 2; c++) {
            f16x8 pa = *(const f16x8*)&Ps[(w * 16 + m_) * 72 + c * 32 + q_ * 8];
            #pragma unroll
            for (int oj = 0; oj < 4; oj++) {
                f16x8 vb = *(const f16x8*)&Vt[(oj * 16 + m_) * 72 + c * 32 + q_ * 8];
                acc[oj] = __builtin_amdgcn_mfma_f32_16x16x32_f16(pa, vb, acc[oj], 0, 0, 0);
            }
        }
    }
    const size_t obase = ((size_t)b * S_SEQ + q0) * D_MODEL + hh * 64;
    #pragma unroll
    for (int r = 0; r < 4; r++) {
        float inv = 1.0f / l_run[r];
        #pragma unroll
        for (int oj = 0; oj < 4; oj++) {
            float v = acc[oj][r] * inv;
            unsigned short vh, vl;
            split1(v, vh, vl);
            size_t idx = obase + (size_t)(w * 16 + q_ * 4 + r) * D_MODEL + oj * 16 + m_;
            outHi[idx] = vh;
            outLo[idx] = vl;
        }
    }
}

// ---------------- Gate: 4 tokens/block, pure shuffle reduce, NO atomics ----------------
__global__ __launch_bounds__(256) void gate_kernel(
    const float* __restrict__ h, const float* __restrict__ gw,
    int* __restrict__ topi, float* __restrict__ gates)
{
    const int w = threadIdx.x >> 6, lane = threadIdx.x & 63;
    const int t = blockIdx.x * 4 + w;
    const float* hr = h + (size_t)t * D_MODEL;
    float acc[N_EXP] = {};
    for (int d = lane; d < D_MODEL; d += 64) {
        float xv = hr[d];
        const float4 g0 = *(const float4*)&gw[(size_t)d * N_EXP];
        const float4 g1 = *(const float4*)&gw[(size_t)d * N_EXP + 4];
        acc[0] += xv * g0.x; acc[1] += xv * g0.y;
        acc[2] += xv * g0.z; acc[3] += xv * g0.w;
        acc[4] += xv * g1.x; acc[5] += xv * g1.y;
        acc[6] += xv * g1.z; acc[7] += xv * g1.w;
    }
    #pragma unroll
    for (int mk = 1; mk < 64; mk <<= 1) {
        #pragma unroll
        for (int e = 0; e < N_EXP; e++) acc[e] += __shfl_xor(acc[e], mk);
    }
    if (lane == 0) {
        int e0 = 0; float v0 = acc[0];
        #pragma unroll
        for (int e = 1; e < N_EXP; e++) if (acc[e] > v0) { v0 = acc[e]; e0 = e; }
        int e1 = -1; float v1 = -INFINITY;
        #pragma unroll
        for (int e = 0; e < N_EXP; e++) if (e != e0 && acc[e] > v1) { v1 = acc[e]; e1 = e; }
        float g0 = 1.0f / (1.0f + __expf(v1 - v0));
        float g1 = 1.0f - g0;
        topi[2 * t] = e0; topi[2 * t + 1] = e1;
        gates[2 * t] = g0; gates[2 * t + 1] = g1;
    }
}

// ---------------- Route: single block, ballot-based histogram + scatter, NO atomics ----------------
__global__ __launch_bounds__(1024) void route_kernel(
    const int* __restrict__ topi, const float* __restrict__ gates,
    int* __restrict__ offs, int* __restrict__ rowtok, float* __restrict__ rowgate)
{
    __shared__ int wcnt[16][N_EXP];
    __shared__ int wbase[16][N_EXP];
    __shared__ int offs_s[N_EXP + 1];
    const int tid = threadIdx.x, w = tid >> 6, lane = tid & 63;
    const unsigned long long lt = (1ULL << lane) - 1ULL;

    int mye[8];
    int cnt[N_EXP] = {};
    #pragma unroll
    for (int r = 0; r < 8; r++) {
        int i = w * 512 + r * 64 + lane;
        int e = topi[i];
        mye[r] = e;
        #pragma unroll
        for (int e8 = 0; e8 < N_EXP; e8++) {
            unsigned long long m = __ballot(e == e8);
            cnt[e8] += (int)__popcll(m);
        }
    }
    if (lane == 0) {
        #pragma unroll
        for (int e8 = 0; e8 < N_EXP; e8++) wcnt[w][e8] = cnt[e8];
    }
    __syncthreads();
    if (tid == 0) {
        int off = 0;
        for (int e8 = 0; e8 < N_EXP; e8++) {
            offs_s[e8] = off;
            int c = 0;
            for (int ww = 0; ww < 16; ww++) c += wcnt[ww][e8];
            off += (c + 127) & ~127;
        }
        offs_s[N_EXP] = off;
        for (int e8 = 0; e8 <= N_EXP; e8++) offs[e8] = offs_s[e8];
    }
    __syncthreads();
    if (tid < 128) {
        int ww = tid >> 3, e8 = tid & 7;
        int bse = offs_s[e8];
        for (int w2 = 0; w2 < ww; w2++) bse += wcnt[w2][e8];
        wbase[ww][e8] = bse;
    }
    __syncthreads();
    int base[N_EXP];
    #pragma unroll
    for (int e8 = 0; e8 < N_EXP; e8++) base[e8] = wbase[w][e8];
    #pragma unroll
    for (int r = 0; r < 8; r++) {
        int i = w * 512 + r * 64 + lane;
        int e = mye[r];
        int pos = 0;
        #pragma unroll
        for (int e8 = 0; e8 < N_EXP; e8++) {
            unsigned long long m = __ballot(e == e8);
            if (e == e8) pos = base[e8] + (int)__popcll(m & lt);
            base[e8] += (int)__popcll(m);
        }
        rowtok[pos] = i >> 1;
        rowgate[pos] = gates[i];
    }
}

extern "C" void kernel_launch(void* const* d_in, const int* in_sizes, int n_in,
                              void* d_out, int out_size, void* d_ws, size_t ws_size,
                              hipStream_t stream)
{
    const float* x0    = (const float*)d_in[0];
    const float* ln1w  = (const float*)d_in[1];
    const float* ln1b  = (const float*)d_in[2];
    const float* wq    = (const float*)d_in[3];
    const float* wk    = (const float*)d_in[4];
    const float* wv    = (const float*)d_in[5];
    const float* wo    = (const float*)d_in[6];
    const float* bo    = (const float*)d_in[7];
    const float* ln2w  = (const float*)d_in[8];
    const float* ln2b  = (const float*)d_in[9];
    const float* gatew = (const float*)d_in[10];
    const float* w1    = (const float*)d_in[11];
    const float* b1    = (const float*)d_in[12];
    const float* w2    = (const float*)d_in[13];
    const float* b2    = (const float*)d_in[14];
    float* out = (float*)d_out;

    // ---- Time-phased workspace (peak ~46.3 MiB, identical layout to R5) ----
    char* ws = (char*)d_ws;
    const size_t MiB = 1 << 20;
    unsigned short* Qh    = (unsigned short*)(ws + 0);
    unsigned short* Kh    = (unsigned short*)(ws + 4 * MiB);
    unsigned short* h_hi  = (unsigned short*)(ws + 8 * MiB);
    unsigned short* h_lo  = (unsigned short*)(ws + 12 * MiB);
    unsigned short* attn_hi = (unsigned short*)(ws + 8 * MiB);
    unsigned short* attn_lo = (unsigned short*)(ws + 12 * MiB);
    float* qkvb = (float*)(ws + 16 * MiB);
    float* x1   = (float*)(ws + 16 * MiB);
    unsigned short* wqkvT_hi = (unsigned short*)(ws + 40 * MiB);
    unsigned short* wqkvT_lo = (unsigned short*)(ws + 40 * MiB + QKV_LD * D_MODEL * 2);
    unsigned short* VTh   = (unsigned short*)(ws + 40 * MiB);
    unsigned short* woT_hi = (unsigned short*)(ws + 44 * MiB);
    unsigned short* woT_lo = (unsigned short*)(ws + 44 * MiB + D_MODEL * D_MODEL * 2);
    unsigned short* h2_hi = (unsigned short*)(ws + 0);
    unsigned short* h2_lo = (unsigned short*)(ws + 4 * MiB);
    unsigned short* h2b   = (unsigned short*)(ws + 0);
    float* h2 = (float*)(ws + 8 * MiB);
    unsigned short* w1T_hi = (unsigned short*)(ws + 8 * MiB);
    unsigned short* w1T_lo = (unsigned short*)(ws + 12 * MiB);
    unsigned short* w2T_hi = (unsigned short*)(ws + 16 * MiB);
    unsigned short* w2T_lo = (unsigned short*)(ws + 20 * MiB);
    unsigned short* hmid_hi = (unsigned short*)(ws + 24 * MiB);
    unsigned short* hmid_lo = (unsigned short*)(ws + 33 * MiB);
    unsigned short* w1T_bf  = (unsigned short*)(ws + 8 * MiB);
    unsigned short* w2T_bf  = (unsigned short*)(ws + 16 * MiB);
    unsigned short* hmidb   = (unsigned short*)(ws + 24 * MiB);
    size_t oI = 46 * MiB;
    int*   topi    = (int*)(ws + oI);
    float* gates   = (float*)(ws + oI + 2 * T_TOK * 4);
    int*   rowtok  = (int*)(ws + oI + 4 * T_TOK * 4);
    float* rowgate = (float*)(ws + oI + 4 * T_TOK * 4 + CAP * 4);
    int*   offs    = (int*)(ws + oI + 4 * T_TOK * 4 + 2 * CAP * 4);
    float* x2 = out;   // inter-layer residual lives in d_out

    const dim3 gW(16, 16, 1);
    const dim3 gW8(16, 16, 8);
    const dim3 gQKV(QKV_LD / 128, T_TOK / 128);   // 12 x 32
    const dim3 gO(D_MODEL / 64, T_TOK / 128);     // 8 x 32
    const dim3 gUp1(8, CAP / 128);                // 8 x 72 (BN=64, CHUNK=512)
    const dim3 gDn1(D_MODEL / 64, CAP / 128);     // 8 x 72
    const dim3 gUp2(1024 / 128, CAP / 128);       // 8 x 72 (BN=128, CHUNK=1024)
    const dim3 gDn2(D_MODEL / 64, CAP / 128);     // 8 x 72
    const dim3 gAttn(S_SEQ / 64, 8, 4);

    for (int l = 0; l < 2; l++) {
        const float* xin = (l == 0) ? x0 : x2;
        float* xout = (l == 1) ? out : x2;
        const float* wq_l = wq + (size_t)l * D_MODEL * D_MODEL;
        const float* wk_l = wk + (size_t)l * D_MODEL * D_MODEL;
        const float* wv_l = wv + (size_t)l * D_MODEL * D_MODEL;
        const float* wo_l = wo + (size_t)l * D_MODEL * D_MODEL;
        const float* w1_l = w1 + (size_t)l * N_EXP * D_MODEL * DH_FF;
        const float* w2_l = w2 + (size_t)l * N_EXP * DH_FF * D_MODEL;
        const float* b1_l = b1 + (size_t)l * N_EXP * DH_FF;
        const float* b2_l = b2 + (size_t)l * N_EXP * D_MODEL;

        ln_kernel<<<T_TOK, 256, 0, stream>>>(xin, ln1w + (size_t)l * D_MODEL,
                                             ln1b + (size_t)l * D_MODEL,
                                             nullptr, h_hi, h_lo, nullptr, nullptr);
        tconv_split<<<gW, 256, 0, stream>>>(wq_l, D_MODEL, 0, wqkvT_hi, wqkvT_lo, D_MODEL, 0);
        tconv_split<<<gW, 256, 0, stream>>>(wk_l, D_MODEL, 0,
                                            wqkvT_hi + 512 * 512, wqkvT_lo + 512 * 512,
                                            D_MODEL, 0);
        tconv_split<<<gW, 256, 0, stream>>>(wv_l, D_MODEL, 0,
                                            wqkvT_hi + 1024 * 512, wqkvT_lo + 1024 * 512,
                                            D_MODEL, 0);
        tconv_split<<<gW, 256, 0, stream>>>(wo_l, D_MODEL, 0, woT_hi, woT_lo, D_MODEL, 0);
        gemm128<0, 128><<<gQKV, 256, 0, stream>>>(h_hi, h_lo, D_MODEL, D_MODEL,
                                                  wqkvT_hi, wqkvT_lo, 0,
                                                  qkvb, QKV_LD, nullptr, 0, nullptr,
                                                  nullptr, nullptr, 0, nullptr, nullptr);
        qkv_prep<<<gAttn, 256, 0, stream>>>(qkvb, Qh, Kh, VTh);
        flash_attn_mfma<<<gAttn, 256, 0, stream>>>(Qh, Kh, VTh, attn_hi, attn_lo);
        gemm128<1, 64><<<gO, 256, 0, stream>>>(attn_hi, attn_lo, D_MODEL, D_MODEL,
                                               woT_hi, woT_lo, 0,
                                               x1, D_MODEL, bo + (size_t)l * D_MODEL, 0,
                                               xin, nullptr, nullptr, 0, nullptr, nullptr);
        ln_kernel<<<T_TOK, 256, 0, stream>>>(x1, ln2w + (size_t)l * D_MODEL,
                                             ln2b + (size_t)l * D_MODEL, h2,
                                             (l == 0) ? h2_hi : nullptr,
                                             (l == 0) ? h2_lo : nullptr,
                                             (l == 1) ? h2b : nullptr, xout);

        hipMemsetAsync(rowtok, 0xFF, CAP * 4, stream);
        gate_kernel<<<T_TOK / 4, 256, 0, stream>>>(h2, gatew + (size_t)l * D_MODEL * N_EXP,
                                                   topi, gates);
        route_kernel<<<1, 1024, 0, stream>>>(topi, gates, offs, rowtok, rowgate);

        if (l == 0) {
            for (int c = 0; c < 4; c++) {
                tconv_split<<<gW8, 256, 0, stream>>>(w1_l + (size_t)c * 512, DH_FF,
                                                     (size_t)D_MODEL * DH_FF,
                                                     w1T_hi, w1T_lo, D_MODEL,
                                                     (size_t)512 * D_MODEL);
                gemm128<2, 64><<<gUp1, 256, 0, stream>>>(h2_hi, h2_lo, D_MODEL, D_MODEL,
                                                         w1T_hi, w1T_lo, (size_t)512 * D_MODEL,
                                                         nullptr, 512,
                                                         b1_l + (size_t)c * 512, DH_FF,
                                                         nullptr, offs, rowtok, 0,
                                                         hmid_hi, hmid_lo);
                tconv_split<<<gW8, 256, 0, stream>>>(w2_l + (size_t)c * 512 * D_MODEL,
                                                     D_MODEL, (size_t)DH_FF * D_MODEL,
                                                     w2T_hi, w2T_lo, 512,
                                                     (size_t)D_MODEL * 512);
                gemm128<5, 64><<<gDn1, 256, 0, stream>>>(hmid_hi, hmid_lo, 512, 512,
                                                         w2T_hi, w2T_lo, (size_t)D_MODEL * 512,
                                                         xout, D_MODEL, b2_l, D_MODEL,
                                                         rowgate, offs, rowtok,
                                                         (c == 0) ? 1 : 0, nullptr, nullptr);
            }
        } else {
            for (int c = 0; c < 2; c++) {
                tconv<<<dim3(32, 16, 8), 256, 0, stream>>>(
                    w1_l + (size_t)c * 1024, DH_FF, (size_t)D_MODEL * DH_FF,
                    w1T_bf, D_MODEL, (size_t)1024 * D_MODEL);
                gemm128_bt<2, 128><<<gUp2, 256, 0, stream>>>(h2b, D_MODEL, D_MODEL,
                                                             w1T_bf, (size_t)1024 * D_MODEL,
                                                             hmidb, 1024,
                                                             b1_l + (size_t)c * 1024, DH_FF,
                                                             offs, rowtok, nullptr, nullptr, 0);
                tconv<<<dim3(16, 32, 8), 256, 0, stream>>>(
                    w2_l + (size_t)c * 1024 * D_MODEL, D_MODEL, (size_t)DH_FF * D_MODEL,
                    w2T_bf, 1024, (size_t)D_MODEL * 1024);
                gemm128_bt<5, 64><<<gDn2, 256, 0, stream>>>(hmidb, 1024, 1024,
                                                            w2T_bf, (size_t)D_MODEL * 1024,
                                                            nullptr, D_MODEL, b2_l, D_MODEL,
                                                            offs, rowtok, rowgate, xout,
                                                            (c == 0) ? 1 : 0);
            }
        }
    }
}

// Round 7
// 884.418 us; speedup vs baseline: 1.7718x; 1.7718x over previous
//
#include <hip/hip_runtime.h>
#include <cmath>

#define D_MODEL 512
#define T_TOK   4096
#define S_SEQ   1024
#define DH_FF   2048
#define N_EXP   8
#define CAP     9216    // 8192 assignments + 8*127 pad, 128-aligned
#define QKV_LD  1536

typedef __attribute__((ext_vector_type(8))) short bf16x8_t;
typedef __attribute__((ext_vector_type(4))) float f32x4_t;
typedef _Float16 f16x8 __attribute__((ext_vector_type(8)));

__device__ __forceinline__ float gelu_exact(float x) {
    return 0.5f * x * (1.0f + erff(x * 0.70710678118654752440f));
}
__device__ __forceinline__ unsigned short f2bf(float f) {
    union { float f; unsigned int u; } v; v.f = f;
    unsigned int r = v.u + 0x7fff + ((v.u >> 16) & 1);   // RNE
    return (unsigned short)(r >> 16);
}
__device__ __forceinline__ float bf2f(unsigned short u) {
    union { unsigned int i; float f; } v; v.i = ((unsigned int)u) << 16; return v.f;
}
__device__ __forceinline__ unsigned short f2h(float f) {
    _Float16 h = (_Float16)f;
    return __builtin_bit_cast(unsigned short, h);
}
// fp32 -> fp16 hi + fp16 lo (Ootomo split): v ~= hi + lo, rel err ~2^-22
__device__ __forceinline__ void split1(float v, unsigned short& h, unsigned short& l) {
    _Float16 hf = (_Float16)v;
    _Float16 lf = (_Float16)(v - (float)hf);
    h = __builtin_bit_cast(unsigned short, hf);
    l = __builtin_bit_cast(unsigned short, lf);
}
// XCD-chunked swizzle: blocks sharing a tile-row land on the same XCD L2.
// Requires nwg % 8 == 0 (all launch grids satisfy this).
__device__ __forceinline__ void xcd_swizzle(int& bx, int& by) {
    const int nwg = gridDim.x * gridDim.y;
    const int bid = blockIdx.y * gridDim.x + blockIdx.x;
    const int swz = (bid & 7) * (nwg >> 3) + (bid >> 3);
    bx = swz % gridDim.x;
    by = swz / gridDim.x;
}

// ---------------- LayerNorm: fp32 in -> optional {fp32, fp16 hi/lo, bf16, xcopy} ----------------
__global__ __launch_bounds__(256) void ln_kernel(
    const float* __restrict__ x, const float* __restrict__ w,
    const float* __restrict__ b, float* __restrict__ outf,
    unsigned short* __restrict__ outHi, unsigned short* __restrict__ outLo,
    unsigned short* __restrict__ outb, float* __restrict__ xcopy)
{
    const int t = blockIdx.x, tid = threadIdx.x;
    const float* xr = x + (size_t)t * D_MODEL;
    float v0 = xr[tid], v1 = xr[tid + 256];
    __shared__ float ss[256], sq[256];
    ss[tid] = v0 + v1;
    sq[tid] = v0 * v0 + v1 * v1;
    __syncthreads();
    for (int st = 128; st > 0; st >>= 1) {
        if (tid < st) { ss[tid] += ss[tid + st]; sq[tid] += sq[tid + st]; }
        __syncthreads();
    }
    float mu  = ss[0] * (1.0f / 512.0f);
    float var = sq[0] * (1.0f / 512.0f) - mu * mu;
    float rs  = rsqrtf(var + 1e-6f);
    float o0 = (v0 - mu) * rs * w[tid]       + b[tid];
    float o1 = (v1 - mu) * rs * w[tid + 256] + b[tid + 256];
    if (outf) {
        float* outr = outf + (size_t)t * D_MODEL;
        outr[tid] = o0; outr[tid + 256] = o1;
    }
    if (outHi) {
        unsigned short h0, l0, h1, l1;
        split1(o0, h0, l0); split1(o1, h1, l1);
        unsigned short* oh = outHi + (size_t)t * D_MODEL;
        unsigned short* ol = outLo + (size_t)t * D_MODEL;
        oh[tid] = h0; oh[tid + 256] = h1;
        ol[tid] = l0; ol[tid + 256] = l1;
    }
    if (outb) {
        unsigned short* ob = outb + (size_t)t * D_MODEL;
        ob[tid] = f2bf(o0); ob[tid + 256] = f2bf(o1);
    }
    if (xcopy) {
        float* xc = xcopy + (size_t)t * D_MODEL;
        xc[tid] = v0; xc[tid + 256] = v1;
    }
}

// ------- Transpose-split: fp32 [K,N] slab -> fp16 hi[N,K] + lo[N,K] (wide grid) -------
__global__ __launch_bounds__(256) void tconv_split(
    const float* __restrict__ in, int inLd, size_t eStrideIn,
    unsigned short* __restrict__ outHi, unsigned short* __restrict__ outLo,
    int outLd, size_t eStrideOut)
{
    __shared__ float Ts[32][33];
    const int tid = threadIdx.x;
    const int k0 = blockIdx.y * 32, n0 = blockIdx.x * 32;
    in    += (size_t)blockIdx.z * eStrideIn;
    outHi += (size_t)blockIdx.z * eStrideOut;
    outLo += (size_t)blockIdx.z * eStrideOut;
    int r = tid >> 3, c = (tid & 7) * 4;
    float4 v = *(const float4*)&in[(size_t)(k0 + r) * inLd + n0 + c];
    Ts[r][c] = v.x; Ts[r][c + 1] = v.y; Ts[r][c + 2] = v.z; Ts[r][c + 3] = v.w;
    __syncthreads();
    int n = tid >> 3, kk = (tid & 7) * 4;
    ushort4 h4, l4;
    split1(Ts[kk][n],     h4.x, l4.x); split1(Ts[kk + 1][n], h4.y, l4.y);
    split1(Ts[kk + 2][n], h4.z, l4.z); split1(Ts[kk + 3][n], h4.w, l4.w);
    size_t o = (size_t)(n0 + n) * outLd + k0 + kk;
    *(ushort4*)&outHi[o] = h4;
    *(ushort4*)&outLo[o] = l4;
}

// ------- Transpose-convert bf16 (L2 MoE weights, wide grid) -------
__global__ __launch_bounds__(256) void tconv(
    const float* __restrict__ in, int inLd, size_t eStrideIn,
    unsigned short* __restrict__ out, int outLd, size_t eStrideOut)
{
    __shared__ float Ts[32][33];
    const int tid = threadIdx.x;
    const int k0 = blockIdx.y * 32, n0 = blockIdx.x * 32;
    in  += (size_t)blockIdx.z * eStrideIn;
    out += (size_t)blockIdx.z * eStrideOut;
    int r = tid >> 3, c = (tid & 7) * 4;
    float4 v = *(const float4*)&in[(size_t)(k0 + r) * inLd + n0 + c];
    Ts[r][c] = v.x; Ts[r][c + 1] = v.y; Ts[r][c + 2] = v.z; Ts[r][c + 3] = v.w;
    __syncthreads();
    int n = tid >> 3, kk = (tid & 7) * 4;
    ushort4 o;
    o.x = f2bf(Ts[kk][n]);     o.y = f2bf(Ts[kk + 1][n]);
    o.z = f2bf(Ts[kk + 2][n]); o.w = f2bf(Ts[kk + 3][n]);
    *(ushort4*)&out[(size_t)(n0 + n) * outLd + k0 + kk] = o;
}

// ================= one-stage fp16x3 MFMA GEMM, 64x64 tiles, K-step 32 =================
// A pre-split hi/lo [M][K] (MODE2: gathered rows); B pre-split hi/lo [N][K] K-contig.
// MODE 0: C fp32 = acc                 (qkv, ldc=1536)
// MODE 1: C fp32 = acc + bias + resid  (o proj)
// MODE 2: Chi/Clo = split(gelu(acc+bias_e)), A gathered via rowtok (MoE up)
// MODE 5: atomicAdd(C[tok], rowgate*(acc + beta?bias_e:0)), skip pads (MoE down)
template<int MODE>
__global__ __launch_bounds__(256) void gemm_pre(
    const unsigned short* __restrict__ Ahi, const unsigned short* __restrict__ Alo,
    int lda, int KLEN,
    const unsigned short* __restrict__ Bhi, const unsigned short* __restrict__ Blo,
    size_t BeStride,
    float* __restrict__ C, int ldc,
    const float* __restrict__ bias, int biasStride,
    const float* __restrict__ resid,
    const int* __restrict__ offs, const int* __restrict__ rowtok, int beta,
    unsigned short* __restrict__ Chi, unsigned short* __restrict__ Clo)
{
    __shared__ unsigned short As_hi[64][40], As_lo[64][40];
    __shared__ unsigned short Bs_hi[64][40], Bs_lo[64][40];
    __shared__ int rt[64];
    __shared__ float rg[64];
    const int tid = threadIdx.x;
    int bx, by;
    xcd_swizzle(bx, by);
    const int row0 = by * 64, col0 = bx * 64;
    int e = 0;
    if (MODE == 2 || MODE == 5) {
        #pragma unroll
        for (int i = 1; i < N_EXP; i++) if (offs[i] <= row0) e = i;
        if (tid < 64) rt[tid] = rowtok[row0 + tid];
        if (MODE == 5 && tid >= 64 && tid < 128) rg[tid - 64] = resid[row0 + tid - 64];
        __syncthreads();
    }
    const unsigned short* BeH = Bhi + (size_t)e * BeStride;
    const unsigned short* BeL = Blo + (size_t)e * BeStride;
    const int lane = tid & 63, w = tid >> 6;
    const int wrow = (w >> 1) * 32, wcol = (w & 1) * 32;
    const int m_ = lane & 15, q_ = lane >> 4;
    f32x4_t acc[2][2];
    #pragma unroll
    for (int i = 0; i < 2; i++)
        #pragma unroll
        for (int j = 0; j < 2; j++) acc[i][j] = (f32x4_t){0.f, 0.f, 0.f, 0.f};

    const int sr = tid >> 2, sc = (tid & 3) * 8;   // 64 rows x 32k: 1 uint4/thread/array
    size_t arow;
    bool azero = false;
    if (MODE == 2) {
        int t = rt[sr];
        azero = (t < 0);
        arow = (size_t)(azero ? 0 : t) * lda;
    } else {
        arow = (size_t)(row0 + sr) * lda;
    }
    const size_t brow = (size_t)(col0 + sr) * KLEN;

    for (int k0 = 0; k0 < KLEN; k0 += 32) {
        uint4 vh = azero ? make_uint4(0u, 0u, 0u, 0u) : *(const uint4*)&Ahi[arow + k0 + sc];
        uint4 vl = azero ? make_uint4(0u, 0u, 0u, 0u) : *(const uint4*)&Alo[arow + k0 + sc];
        *(uint4*)&As_hi[sr][sc] = vh;
        *(uint4*)&As_lo[sr][sc] = vl;
        *(uint4*)&Bs_hi[sr][sc] = *(const uint4*)&BeH[brow + k0 + sc];
        *(uint4*)&Bs_lo[sr][sc] = *(const uint4*)&BeL[brow + k0 + sc];
        __syncthreads();
        f16x8 ah[2], al[2], bh[2], bl[2];
        #pragma unroll
        for (int i = 0; i < 2; i++) {
            int r = wrow + 16 * i + m_;
            ah[i] = *(const f16x8*)&As_hi[r][q_ * 8];
            al[i] = *(const f16x8*)&As_lo[r][q_ * 8];
        }
        #pragma unroll
        for (int j = 0; j < 2; j++) {
            int r = wcol + 16 * j + m_;
            bh[j] = *(const f16x8*)&Bs_hi[r][q_ * 8];
            bl[j] = *(const f16x8*)&Bs_lo[r][q_ * 8];
        }
        #pragma unroll
        for (int i = 0; i < 2; i++)
            #pragma unroll
            for (int j = 0; j < 2; j++) {
                acc[i][j] = __builtin_amdgcn_mfma_f32_16x16x32_f16(ah[i], bl[j], acc[i][j], 0, 0, 0);
                acc[i][j] = __builtin_amdgcn_mfma_f32_16x16x32_f16(al[i], bh[j], acc[i][j], 0, 0, 0);
                acc[i][j] = __builtin_amdgcn_mfma_f32_16x16x32_f16(ah[i], bh[j], acc[i][j], 0, 0, 0);
            }
        __syncthreads();
    }
    // C/D layout: col = lane&15, row = (lane>>4)*4 + reg  [validated r4]
    #pragma unroll
    for (int i = 0; i < 2; i++) {
        #pragma unroll
        for (int j = 0; j < 2; j++) {
            #pragma unroll
            for (int r = 0; r < 4; r++) {
                int lr = wrow + 16 * i + q_ * 4 + r;
                int gr = row0 + lr;
                int gc = col0 + wcol + 16 * j + m_;
                float v = acc[i][j][r];
                if (MODE == 5) {
                    int t = rt[lr];
                    if (t >= 0) {
                        float add = beta ? bias[(size_t)e * biasStride + gc] : 0.0f;
                        atomicAdd(&C[(size_t)t * ldc + gc], rg[lr] * (v + add));
                    }
                } else if (MODE == 2) {
                    float g = gelu_exact(v + bias[(size_t)e * biasStride + gc]);
                    unsigned short gh, gl;
                    split1(g, gh, gl);
                    size_t idx = (size_t)gr * ldc + gc;
                    Chi[idx] = gh; Clo[idx] = gl;
                } else {
                    size_t idx = (size_t)gr * ldc + gc;
                    if (MODE == 1) C[idx] = v + bias[gc] + resid[idx];
                    else           C[idx] = v;
                }
            }
        }
    }
}

// ================= one-stage bf16 MFMA GEMM (L2 MoE), 64x64 tiles, K-step 64 =========
// MODE 2: C bf16 = gelu(acc+bias_e), A bf16 gathered via rowtok (MoE up)
// MODE 5: atomicAdd(Cout[tok], rowgate*(acc + beta?bias_e:0)), skip pads
template<int MODE>
__global__ __launch_bounds__(256) void gemm_pre_bt(
    const unsigned short* __restrict__ A, int lda, int KLEN,
    const unsigned short* __restrict__ Bt, size_t BeStride,
    unsigned short* __restrict__ C, int ldc,
    const float* __restrict__ biasBase, int biasStride,
    const int* __restrict__ offs, const int* __restrict__ rowtok,
    const float* __restrict__ rowgate, float* __restrict__ Cout, int beta)
{
    __shared__ unsigned short As[64][72];
    __shared__ unsigned short Bs[64][72];
    __shared__ int rt[64];
    __shared__ float rg[64];
    const int tid = threadIdx.x;
    int bx, by;
    xcd_swizzle(bx, by);
    const int row0 = by * 64, col0 = bx * 64;
    int e = 0;
    #pragma unroll
    for (int i = 1; i < N_EXP; i++) if (offs[i] <= row0) e = i;
    if (tid < 64) rt[tid] = rowtok[row0 + tid];
    if (MODE == 5 && tid >= 64 && tid < 128) rg[tid - 64] = rowgate[row0 + tid - 64];
    __syncthreads();
    const unsigned short* Be = Bt + (size_t)e * BeStride;
    const int lane = tid & 63, w = tid >> 6;
    const int wrow = (w >> 1) * 32, wcol = (w & 1) * 32;
    const int m_ = lane & 15, q_ = lane >> 4;
    f32x4_t acc[2][2];
    #pragma unroll
    for (int i = 0; i < 2; i++)
        #pragma unroll
        for (int j = 0; j < 2; j++) acc[i][j] = (f32x4_t){0.f, 0.f, 0.f, 0.f};

    const int sr = tid >> 3, sc = (tid & 7) * 8;   // 64 rows x 64k: 2 uint4/thread/array
    size_t arow0, arow1;
    bool az0 = false, az1 = false;
    {
        int r1 = sr + 32;
        if (MODE == 2) {
            int t0 = rt[sr], t1 = rt[r1];
            az0 = (t0 < 0); az1 = (t1 < 0);
            arow0 = (size_t)(az0 ? 0 : t0) * lda;
            arow1 = (size_t)(az1 ? 0 : t1) * lda;
        } else {
            arow0 = (size_t)(row0 + sr) * lda;
            arow1 = (size_t)(row0 + r1) * lda;
        }
    }
    const size_t brow0 = (size_t)(col0 + sr) * KLEN;
    const size_t brow1 = (size_t)(col0 + sr + 32) * KLEN;

    for (int k0 = 0; k0 < KLEN; k0 += 64) {
        uint4 a0 = az0 ? make_uint4(0u, 0u, 0u, 0u) : *(const uint4*)&A[arow0 + k0 + sc];
        uint4 a1 = az1 ? make_uint4(0u, 0u, 0u, 0u) : *(const uint4*)&A[arow1 + k0 + sc];
        *(uint4*)&As[sr][sc]      = a0;
        *(uint4*)&As[sr + 32][sc] = a1;
        *(uint4*)&Bs[sr][sc]      = *(const uint4*)&Be[brow0 + k0 + sc];
        *(uint4*)&Bs[sr + 32][sc] = *(const uint4*)&Be[brow1 + k0 + sc];
        __syncthreads();
        #pragma unroll
        for (int ks = 0; ks < 2; ks++) {
            bf16x8_t af[2], bfr[2];
            #pragma unroll
            for (int i = 0; i < 2; i++)
                af[i] = *(const bf16x8_t*)&As[wrow + 16 * i + m_][ks * 32 + q_ * 8];
            #pragma unroll
            for (int j = 0; j < 2; j++)
                bfr[j] = *(const bf16x8_t*)&Bs[wcol + 16 * j + m_][ks * 32 + q_ * 8];
            #pragma unroll
            for (int i = 0; i < 2; i++)
                #pragma unroll
                for (int j = 0; j < 2; j++)
                    acc[i][j] = __builtin_amdgcn_mfma_f32_16x16x32_bf16(
                        af[i], bfr[j], acc[i][j], 0, 0, 0);
        }
        __syncthreads();
    }
    #pragma unroll
    for (int i = 0; i < 2; i++) {
        #pragma unroll
        for (int j = 0; j < 2; j++) {
            #pragma unroll
            for (int r = 0; r < 4; r++) {
                int lr = wrow + 16 * i + q_ * 4 + r;
                int gr = row0 + lr;
                int gc = col0 + wcol + 16 * j + m_;
                float v = acc[i][j][r];
                if (MODE == 5) {
                    int t = rt[lr];
                    if (t >= 0) {
                        float add = beta ? biasBase[(size_t)e * biasStride + gc] : 0.0f;
                        atomicAdd(&Cout[(size_t)t * ldc + gc], rg[lr] * (v + add));
                    }
                } else {
                    C[(size_t)gr * ldc + gc] =
                        f2bf(gelu_exact(v + biasBase[(size_t)e * biasStride + gc]));
                }
            }
        }
    }
}

// ---------------- QKV prep: fp32 qkvb slab -> fp16 head-major Q (x0.125), K, V^T ----------------
__global__ __launch_bounds__(256) void qkv_prep(
    const float* __restrict__ qkvb, unsigned short* __restrict__ Qh,
    unsigned short* __restrict__ Kh, unsigned short* __restrict__ VTh)
{
    __shared__ float Ts[64][65];
    const int tid = threadIdx.x;
    const int t0 = blockIdx.x * 64, hh = blockIdx.y, b = blockIdx.z;
    const int bh = b * 8 + hh;
    const float* src = qkvb + ((size_t)(b * S_SEQ + t0)) * QKV_LD + hh * 64;
    #pragma unroll
    for (int i = 0; i < 4; i++) {
        int flat = tid + i * 256;
        int r = flat >> 4, c4 = (flat & 15) * 4;
        float4 qv = *(const float4*)&src[(size_t)r * QKV_LD + c4];
        float4 kv = *(const float4*)&src[(size_t)r * QKV_LD + 512 + c4];
        float4 vv = *(const float4*)&src[(size_t)r * QKV_LD + 1024 + c4];
        ushort4 qo, ko;
        qo.x = f2h(qv.x * 0.125f); qo.y = f2h(qv.y * 0.125f);
        qo.z = f2h(qv.z * 0.125f); qo.w = f2h(qv.w * 0.125f);
        ko.x = f2h(kv.x); ko.y = f2h(kv.y); ko.z = f2h(kv.z); ko.w = f2h(kv.w);
        size_t o = ((size_t)bh * S_SEQ + t0 + r) * 64 + c4;
        *(ushort4*)&Qh[o] = qo;
        *(ushort4*)&Kh[o] = ko;
        Ts[r][c4] = vv.x; Ts[r][c4 + 1] = vv.y; Ts[r][c4 + 2] = vv.z; Ts[r][c4 + 3] = vv.w;
    }
    __syncthreads();
    #pragma unroll
    for (int i = 0; i < 4; i++) {
        int flat = tid + i * 256;
        int d = flat >> 4, s4 = (flat & 15) * 4;
        ushort4 vo;
        vo.x = f2h(Ts[s4][d]);     vo.y = f2h(Ts[s4 + 1][d]);
        vo.z = f2h(Ts[s4 + 2][d]); vo.w = f2h(Ts[s4 + 3][d]);
        *(ushort4*)&VTh[((size_t)bh * 64 + d) * S_SEQ + t0 + s4] = vo;
    }
}

// ---------------- Flash attention, fp16 MFMA; epilogue emits hi/lo split ----------------
__global__ __launch_bounds__(256) void flash_attn_mfma(
    const unsigned short* __restrict__ Qh, const unsigned short* __restrict__ Kh,
    const unsigned short* __restrict__ VTh,
    unsigned short* __restrict__ outHi, unsigned short* __restrict__ outLo)
{
    __shared__ unsigned short Ks[64 * 72];
    __shared__ unsigned short Vt[64 * 72];
    __shared__ unsigned short Ps[64 * 72];
    const int tid = threadIdx.x;
    const int lane = tid & 63, w = tid >> 6;
    const int m_ = lane & 15, q_ = lane >> 4;
    const int hh = blockIdx.y, b = blockIdx.z;
    const int bh = b * 8 + hh;
    const int q0 = blockIdx.x * 64;
    const size_t qbase = ((size_t)bh * S_SEQ + q0) * 64;
    const size_t kbase = (size_t)bh * S_SEQ * 64;
    const size_t vbase = (size_t)bh * 64 * S_SEQ;

    f16x8 qa[2];
    #pragma unroll
    for (int c = 0; c < 2; c++)
        qa[c] = *(const f16x8*)&Qh[qbase + (size_t)(w * 16 + m_) * 64 + c * 32 + q_ * 8];

    float m_run[4], l_run[4];
    f32x4_t acc[4];
    #pragma unroll
    for (int r = 0; r < 4; r++) { m_run[r] = -INFINITY; l_run[r] = 0.0f; }
    #pragma unroll
    for (int oj = 0; oj < 4; oj++) acc[oj] = (f32x4_t){0.f, 0.f, 0.f, 0.f};

    for (int kv0 = 0; kv0 < S_SEQ; kv0 += 64) {
        __syncthreads();
        #pragma unroll
        for (int i = 0; i < 2; i++) {
            int g = tid + i * 256;
            int r = g >> 3, c8 = (g & 7) * 8;
            *(uint4*)&Ks[r * 72 + c8] =
                *(const uint4*)&Kh[kbase + (size_t)(kv0 + r) * 64 + c8];
            *(uint4*)&Vt[r * 72 + c8] =
                *(const uint4*)&VTh[vbase + (size_t)r * S_SEQ + kv0 + c8];
        }
        __syncthreads();
        f32x4_t s[4];
        #pragma unroll
        for (int j = 0; j < 4; j++) s[j] = (f32x4_t){0.f, 0.f, 0.f, 0.f};
        #pragma unroll
        for (int c = 0; c < 2; c++)
            #pragma unroll
            for (int j = 0; j < 4; j++) {
                f16x8 kb = *(const f16x8*)&Ks[(j * 16 + m_) * 72 + c * 32 + q_ * 8];
                s[j] = __builtin_amdgcn_mfma_f32_16x16x32_f16(qa[c], kb, s[j], 0, 0, 0);
            }
        float alpha[4];
        #pragma unroll
        for (int r = 0; r < 4; r++) {
            float rm = fmaxf(fmaxf(s[0][r], s[1][r]), fmaxf(s[2][r], s[3][r]));
            #pragma unroll
            for (int mk = 1; mk < 16; mk <<= 1)
                rm = fmaxf(rm, __shfl_xor(rm, mk));
            float mn = fmaxf(m_run[r], rm);
            alpha[r] = __expf(m_run[r] - mn);
            m_run[r] = mn;
            float ps = 0.0f;
            #pragma unroll
            for (int j = 0; j < 4; j++) {
                float p = __expf(s[j][r] - mn);
                s[j][r] = p;
                ps += p;
            }
            #pragma unroll
            for (int mk = 1; mk < 16; mk <<= 1)
                ps += __shfl_xor(ps, mk);
            l_run[r] = l_run[r] * alpha[r] + ps;
        }
        #pragma unroll
        for (int oj = 0; oj < 4; oj++)
            #pragma unroll
            for (int r = 0; r < 4; r++)
                acc[oj][r] *= alpha[r];
        #pragma unroll
        for (int j = 0; j < 4; j++)
            #pragma unroll
            for (int r = 0; r < 4; r++)
                Ps[(w * 16 + q_ * 4 + r) * 72 + j * 16 + m_] = f2h(s[j][r]);
        __syncthreads();
        #pragma unroll
        for (int c = 0; c < 2; c++) {
            f16x8 pa = *(const f16x8*)&Ps[(w * 16 + m_) * 72 + c * 32 + q_ * 8];
            #pragma unroll
            for (int oj = 0; oj < 4; oj++) {
                f16x8 vb = *(const f16x8*)&Vt[(oj * 16 + m_) * 72 + c * 32 + q_ * 8];
                acc[oj] = __builtin_amdgcn_mfma_f32_16x16x32_f16(pa, vb, acc[oj], 0, 0, 0);
            }
        }
    }
    const size_t obase = ((size_t)b * S_SEQ + q0) * D_MODEL + hh * 64;
    #pragma unroll
    for (int r = 0; r < 4; r++) {
        float inv = 1.0f / l_run[r];
        #pragma unroll
        for (int oj = 0; oj < 4; oj++) {
            float v = acc[oj][r] * inv;
            unsigned short vh, vl;
            split1(v, vh, vl);
            size_t idx = obase + (size_t)(w * 16 + q_ * 4 + r) * D_MODEL + oj * 16 + m_;
            outHi[idx] = vh;
            outLo[idx] = vl;
        }
    }
}

// ---------------- Gate: 4 tokens/block, pure shuffle reduce, NO atomics ----------------
__global__ __launch_bounds__(256) void gate_kernel(
    const float* __restrict__ h, const float* __restrict__ gw,
    int* __restrict__ topi, float* __restrict__ gates)
{
    const int w = threadIdx.x >> 6, lane = threadIdx.x & 63;
    const int t = blockIdx.x * 4 + w;
    const float* hr = h + (size_t)t * D_MODEL;
    float acc[N_EXP] = {};
    for (int d = lane; d < D_MODEL; d += 64) {
        float xv = hr[d];
        const float4 g0 = *(const float4*)&gw[(size_t)d * N_EXP];
        const float4 g1 = *(const float4*)&gw[(size_t)d * N_EXP + 4];
        acc[0] += xv * g0.x; acc[1] += xv * g0.y;
        acc[2] += xv * g0.z; acc[3] += xv * g0.w;
        acc[4] += xv * g1.x; acc[5] += xv * g1.y;
        acc[6] += xv * g1.z; acc[7] += xv * g1.w;
    }
    #pragma unroll
    for (int mk = 1; mk < 64; mk <<= 1) {
        #pragma unroll
        for (int e = 0; e < N_EXP; e++) acc[e] += __shfl_xor(acc[e], mk);
    }
    if (lane == 0) {
        int e0 = 0; float v0 = acc[0];
        #pragma unroll
        for (int e = 1; e < N_EXP; e++) if (acc[e] > v0) { v0 = acc[e]; e0 = e; }
        int e1 = -1; float v1 = -INFINITY;
        #pragma unroll
        for (int e = 0; e < N_EXP; e++) if (e != e0 && acc[e] > v1) { v1 = acc[e]; e1 = e; }
        float g0 = 1.0f / (1.0f + __expf(v1 - v0));
        float g1 = 1.0f - g0;
        topi[2 * t] = e0; topi[2 * t + 1] = e1;
        gates[2 * t] = g0; gates[2 * t + 1] = g1;
    }
}

// ---------------- Route: single block, ballot-based histogram + scatter, NO atomics ----------------
__global__ __launch_bounds__(1024) void route_kernel(
    const int* __restrict__ topi, const float* __restrict__ gates,
    int* __restrict__ offs, int* __restrict__ rowtok, float* __restrict__ rowgate)
{
    __shared__ int wcnt[16][N_EXP];
    __shared__ int wbase[16][N_EXP];
    __shared__ int offs_s[N_EXP + 1];
    const int tid = threadIdx.x, w = tid >> 6, lane = tid & 63;
    const unsigned long long lt = (1ULL << lane) - 1ULL;

    int mye[8];
    int cnt[N_EXP] = {};
    #pragma unroll
    for (int r = 0; r < 8; r++) {
        int i = w * 512 + r * 64 + lane;
        int e = topi[i];
        mye[r] = e;
        #pragma unroll
        for (int e8 = 0; e8 < N_EXP; e8++) {
            unsigned long long m = __ballot(e == e8);
            cnt[e8] += (int)__popcll(m);
        }
    }
    if (lane == 0) {
        #pragma unroll
        for (int e8 = 0; e8 < N_EXP; e8++) wcnt[w][e8] = cnt[e8];
    }
    __syncthreads();
    if (tid == 0) {
        int off = 0;
        for (int e8 = 0; e8 < N_EXP; e8++) {
            offs_s[e8] = off;
            int c = 0;
            for (int ww = 0; ww < 16; ww++) c += wcnt[ww][e8];
            off += (c + 127) & ~127;
        }
        offs_s[N_EXP] = off;
        for (int e8 = 0; e8 <= N_EXP; e8++) offs[e8] = offs_s[e8];
    }
    __syncthreads();
    if (tid < 128) {
        int ww = tid >> 3, e8 = tid & 7;
        int bse = offs_s[e8];
        for (int w2 = 0; w2 < ww; w2++) bse += wcnt[w2][e8];
        wbase[ww][e8] = bse;
    }
    __syncthreads();
    int base[N_EXP];
    #pragma unroll
    for (int e8 = 0; e8 < N_EXP; e8++) base[e8] = wbase[w][e8];
    #pragma unroll
    for (int r = 0; r < 8; r++) {
        int i = w * 512 + r * 64 + lane;
        int e = mye[r];
        int pos = 0;
        #pragma unroll
        for (int e8 = 0; e8 < N_EXP; e8++) {
            unsigned long long m = __ballot(e == e8);
            if (e == e8) pos = base[e8] + (int)__popcll(m & lt);
            base[e8] += (int)__popcll(m);
        }
        rowtok[pos] = i >> 1;
        rowgate[pos] = gates[i];
    }
}

extern "C" void kernel_launch(void* const* d_in, const int* in_sizes, int n_in,
                              void* d_out, int out_size, void* d_ws, size_t ws_size,
                              hipStream_t stream)
{
    const float* x0    = (const float*)d_in[0];
    const float* ln1w  = (const float*)d_in[1];
    const float* ln1b  = (const float*)d_in[2];
    const float* wq    = (const float*)d_in[3];
    const float* wk    = (const float*)d_in[4];
    const float* wv    = (const float*)d_in[5];
    const float* wo    = (const float*)d_in[6];
    const float* bo    = (const float*)d_in[7];
    const float* ln2w  = (const float*)d_in[8];
    const float* ln2b  = (const float*)d_in[9];
    const float* gatew = (const float*)d_in[10];
    const float* w1    = (const float*)d_in[11];
    const float* b1    = (const float*)d_in[12];
    const float* w2    = (const float*)d_in[13];
    const float* b2    = (const float*)d_in[14];
    float* out = (float*)d_out;

    // ---- Time-phased workspace (peak ~46.3 MiB, identical layout to R4) ----
    char* ws = (char*)d_ws;
    const size_t MiB = 1 << 20;
    unsigned short* Qh    = (unsigned short*)(ws + 0);
    unsigned short* Kh    = (unsigned short*)(ws + 4 * MiB);
    unsigned short* h_hi  = (unsigned short*)(ws + 8 * MiB);
    unsigned short* h_lo  = (unsigned short*)(ws + 12 * MiB);
    unsigned short* attn_hi = (unsigned short*)(ws + 8 * MiB);
    unsigned short* attn_lo = (unsigned short*)(ws + 12 * MiB);
    float* qkvb = (float*)(ws + 16 * MiB);
    float* x1   = (float*)(ws + 16 * MiB);
    unsigned short* wqkvT_hi = (unsigned short*)(ws + 40 * MiB);
    unsigned short* wqkvT_lo = (unsigned short*)(ws + 40 * MiB + QKV_LD * D_MODEL * 2);
    unsigned short* VTh   = (unsigned short*)(ws + 40 * MiB);
    unsigned short* woT_hi = (unsigned short*)(ws + 44 * MiB);
    unsigned short* woT_lo = (unsigned short*)(ws + 44 * MiB + D_MODEL * D_MODEL * 2);
    unsigned short* h2_hi = (unsigned short*)(ws + 0);
    unsigned short* h2_lo = (unsigned short*)(ws + 4 * MiB);
    unsigned short* h2b   = (unsigned short*)(ws + 0);
    float* h2 = (float*)(ws + 8 * MiB);
    unsigned short* w1T_hi = (unsigned short*)(ws + 8 * MiB);
    unsigned short* w1T_lo = (unsigned short*)(ws + 12 * MiB);
    unsigned short* w2T_hi = (unsigned short*)(ws + 16 * MiB);
    unsigned short* w2T_lo = (unsigned short*)(ws + 20 * MiB);
    unsigned short* hmid_hi = (unsigned short*)(ws + 24 * MiB);
    unsigned short* hmid_lo = (unsigned short*)(ws + 33 * MiB);
    unsigned short* w1T_bf  = (unsigned short*)(ws + 8 * MiB);
    unsigned short* w2T_bf  = (unsigned short*)(ws + 16 * MiB);
    unsigned short* hmidb   = (unsigned short*)(ws + 24 * MiB);
    size_t oI = 46 * MiB;
    int*   topi    = (int*)(ws + oI);
    float* gates   = (float*)(ws + oI + 2 * T_TOK * 4);
    int*   rowtok  = (int*)(ws + oI + 4 * T_TOK * 4);
    float* rowgate = (float*)(ws + oI + 4 * T_TOK * 4 + CAP * 4);
    int*   offs    = (int*)(ws + oI + 4 * T_TOK * 4 + 2 * CAP * 4);
    float* x2 = out;   // inter-layer residual lives in d_out

    const dim3 gW(16, 16, 1);
    const dim3 gW8(16, 16, 8);
    const dim3 gQKV(QKV_LD / 64, T_TOK / 64);    // 24 x 64 = 1536
    const dim3 gO(D_MODEL / 64, T_TOK / 64);     // 8 x 64 = 512
    const dim3 gUp1(8, CAP / 64);                // 8 x 144 = 1152 (CHUNK=512)
    const dim3 gDn1(D_MODEL / 64, CAP / 64);     // 1152
    const dim3 gUp2(16, CAP / 64);               // 2304 (CHUNK=1024)
    const dim3 gDn2(D_MODEL / 64, CAP / 64);     // 1152
    const dim3 gAttn(S_SEQ / 64, 8, 4);

    for (int l = 0; l < 2; l++) {
        const float* xin = (l == 0) ? x0 : x2;
        float* xout = (l == 1) ? out : x2;
        const float* wq_l = wq + (size_t)l * D_MODEL * D_MODEL;
        const float* wk_l = wk + (size_t)l * D_MODEL * D_MODEL;
        const float* wv_l = wv + (size_t)l * D_MODEL * D_MODEL;
        const float* wo_l = wo + (size_t)l * D_MODEL * D_MODEL;
        const float* w1_l = w1 + (size_t)l * N_EXP * D_MODEL * DH_FF;
        const float* w2_l = w2 + (size_t)l * N_EXP * DH_FF * D_MODEL;
        const float* b1_l = b1 + (size_t)l * N_EXP * DH_FF;
        const float* b2_l = b2 + (size_t)l * N_EXP * D_MODEL;

        ln_kernel<<<T_TOK, 256, 0, stream>>>(xin, ln1w + (size_t)l * D_MODEL,
                                             ln1b + (size_t)l * D_MODEL,
                                             nullptr, h_hi, h_lo, nullptr, nullptr);
        tconv_split<<<gW, 256, 0, stream>>>(wq_l, D_MODEL, 0, wqkvT_hi, wqkvT_lo, D_MODEL, 0);
        tconv_split<<<gW, 256, 0, stream>>>(wk_l, D_MODEL, 0,
                                            wqkvT_hi + 512 * 512, wqkvT_lo + 512 * 512,
                                            D_MODEL, 0);
        tconv_split<<<gW, 256, 0, stream>>>(wv_l, D_MODEL, 0,
                                            wqkvT_hi + 1024 * 512, wqkvT_lo + 1024 * 512,
                                            D_MODEL, 0);
        tconv_split<<<gW, 256, 0, stream>>>(wo_l, D_MODEL, 0, woT_hi, woT_lo, D_MODEL, 0);
        gemm_pre<0><<<gQKV, 256, 0, stream>>>(h_hi, h_lo, D_MODEL, D_MODEL,
                                              wqkvT_hi, wqkvT_lo, 0,
                                              qkvb, QKV_LD, nullptr, 0, nullptr,
                                              nullptr, nullptr, 0, nullptr, nullptr);
        qkv_prep<<<gAttn, 256, 0, stream>>>(qkvb, Qh, Kh, VTh);
        flash_attn_mfma<<<gAttn, 256, 0, stream>>>(Qh, Kh, VTh, attn_hi, attn_lo);
        gemm_pre<1><<<gO, 256, 0, stream>>>(attn_hi, attn_lo, D_MODEL, D_MODEL,
                                            woT_hi, woT_lo, 0,
                                            x1, D_MODEL, bo + (size_t)l * D_MODEL, 0,
                                            xin, nullptr, nullptr, 0, nullptr, nullptr);
        ln_kernel<<<T_TOK, 256, 0, stream>>>(x1, ln2w + (size_t)l * D_MODEL,
                                             ln2b + (size_t)l * D_MODEL, h2,
                                             (l == 0) ? h2_hi : nullptr,
                                             (l == 0) ? h2_lo : nullptr,
                                             (l == 1) ? h2b : nullptr, xout);

        hipMemsetAsync(rowtok, 0xFF, CAP * 4, stream);
        gate_kernel<<<T_TOK / 4, 256, 0, stream>>>(h2, gatew + (size_t)l * D_MODEL * N_EXP,
                                                   topi, gates);
        route_kernel<<<1, 1024, 0, stream>>>(topi, gates, offs, rowtok, rowgate);

        if (l == 0) {
            for (int c = 0; c < 4; c++) {
                tconv_split<<<gW8, 256, 0, stream>>>(w1_l + (size_t)c * 512, DH_FF,
                                                     (size_t)D_MODEL * DH_FF,
                                                     w1T_hi, w1T_lo, D_MODEL,
                                                     (size_t)512 * D_MODEL);
                gemm_pre<2><<<gUp1, 256, 0, stream>>>(h2_hi, h2_lo, D_MODEL, D_MODEL,
                                                      w1T_hi, w1T_lo, (size_t)512 * D_MODEL,
                                                      nullptr, 512,
                                                      b1_l + (size_t)c * 512, DH_FF,
                                                      nullptr, offs, rowtok, 0,
                                                      hmid_hi, hmid_lo);
                tconv_split<<<gW8, 256, 0, stream>>>(w2_l + (size_t)c * 512 * D_MODEL,
                                                     D_MODEL, (size_t)DH_FF * D_MODEL,
                                                     w2T_hi, w2T_lo, 512,
                                                     (size_t)D_MODEL * 512);
                gemm_pre<5><<<gDn1, 256, 0, stream>>>(hmid_hi, hmid_lo, 512, 512,
                                                      w2T_hi, w2T_lo, (size_t)D_MODEL * 512,
                                                      xout, D_MODEL, b2_l, D_MODEL,
                                                      rowgate, offs, rowtok,
                                                      (c == 0) ? 1 : 0, nullptr, nullptr);
            }
        } else {
            for (int c = 0; c < 2; c++) {
                tconv<<<dim3(32, 16, 8), 256, 0, stream>>>(
                    w1_l + (size_t)c * 1024, DH_FF, (size_t)D_MODEL * DH_FF,
                    w1T_bf, D_MODEL, (size_t)1024 * D_MODEL);
                gemm_pre_bt<2><<<gUp2, 256, 0, stream>>>(h2b, D_MODEL, D_MODEL,
                                                         w1T_bf, (size_t)1024 * D_MODEL,
                                                         hmidb, 1024,
                                                         b1_l + (size_t)c * 1024, DH_FF,
                                                         offs, rowtok, nullptr, nullptr, 0);
                tconv<<<dim3(16, 32, 8), 256, 0, stream>>>(
                    w2_l + (size_t)c * 1024 * D_MODEL, D_MODEL, (size_t)DH_FF * D_MODEL,
                    w2T_bf, 1024, (size_t)D_MODEL * 1024);
                gemm_pre_bt<5><<<gDn2, 256, 0, stream>>>(hmidb, 1024, 1024,
                                                         w2T_bf, (size_t)D_MODEL * 1024,
                                                         nullptr, D_MODEL, b2_l, D_MODEL,
                                                         offs, rowtok, rowgate, xout,
                                                         (c == 0) ? 1 : 0);
            }
        }
    }
}

// Round 8
// 873.274 us; speedup vs baseline: 1.7944x; 1.0128x over previous
//
#include <hip/hip_runtime.h>
#include <cmath>

#define D_MODEL 512
#define T_TOK   4096
#define S_SEQ   1024
#define DH_FF   2048
#define N_EXP   8
#define CAP     9216    // 8192 assignments + 8*127 pad, 128-aligned
#define QKV_LD  1536

typedef __attribute__((ext_vector_type(8))) short bf16x8_t;
typedef __attribute__((ext_vector_type(4))) float f32x4_t;
typedef _Float16 f16x8 __attribute__((ext_vector_type(8)));

__device__ __forceinline__ float gelu_exact(float x) {
    return 0.5f * x * (1.0f + erff(x * 0.70710678118654752440f));
}
__device__ __forceinline__ unsigned short f2bf(float f) {
    union { float f; unsigned int u; } v; v.f = f;
    unsigned int r = v.u + 0x7fff + ((v.u >> 16) & 1);   // RNE
    return (unsigned short)(r >> 16);
}
__device__ __forceinline__ float bf2f(unsigned short u) {
    union { unsigned int i; float f; } v; v.i = ((unsigned int)u) << 16; return v.f;
}
__device__ __forceinline__ unsigned short f2h(float f) {
    _Float16 h = (_Float16)f;
    return __builtin_bit_cast(unsigned short, h);
}
// fp32 -> fp16 hi + fp16 lo (Ootomo split): v ~= hi + lo, rel err ~2^-22
__device__ __forceinline__ void split1(float v, unsigned short& h, unsigned short& l) {
    _Float16 hf = (_Float16)v;
    _Float16 lf = (_Float16)(v - (float)hf);
    h = __builtin_bit_cast(unsigned short, hf);
    l = __builtin_bit_cast(unsigned short, lf);
}
// XCD-chunked swizzle: blocks sharing a tile-row land on the same XCD L2.
// Requires nwg % 8 == 0 (all launch grids satisfy this).
__device__ __forceinline__ void xcd_swizzle(int& bx, int& by) {
    const int nwg = gridDim.x * gridDim.y;
    const int bid = blockIdx.y * gridDim.x + blockIdx.x;
    const int swz = (bid & 7) * (nwg >> 3) + (bid >> 3);
    bx = swz % gridDim.x;
    by = swz / gridDim.x;
}

// ---------------- LayerNorm: fp32 in -> optional {fp32, fp16 hi/lo, bf16, xcopy} ----------------
__global__ __launch_bounds__(256) void ln_kernel(
    const float* __restrict__ x, const float* __restrict__ w,
    const float* __restrict__ b, float* __restrict__ outf,
    unsigned short* __restrict__ outHi, unsigned short* __restrict__ outLo,
    unsigned short* __restrict__ outb, float* __restrict__ xcopy)
{
    const int t = blockIdx.x, tid = threadIdx.x;
    const float* xr = x + (size_t)t * D_MODEL;
    float v0 = xr[tid], v1 = xr[tid + 256];
    __shared__ float ss[256], sq[256];
    ss[tid] = v0 + v1;
    sq[tid] = v0 * v0 + v1 * v1;
    __syncthreads();
    for (int st = 128; st > 0; st >>= 1) {
        if (tid < st) { ss[tid] += ss[tid + st]; sq[tid] += sq[tid + st]; }
        __syncthreads();
    }
    float mu  = ss[0] * (1.0f / 512.0f);
    float var = sq[0] * (1.0f / 512.0f) - mu * mu;
    float rs  = rsqrtf(var + 1e-6f);
    float o0 = (v0 - mu) * rs * w[tid]       + b[tid];
    float o1 = (v1 - mu) * rs * w[tid + 256] + b[tid + 256];
    if (outf) {
        float* outr = outf + (size_t)t * D_MODEL;
        outr[tid] = o0; outr[tid + 256] = o1;
    }
    if (outHi) {
        unsigned short h0, l0, h1, l1;
        split1(o0, h0, l0); split1(o1, h1, l1);
        unsigned short* oh = outHi + (size_t)t * D_MODEL;
        unsigned short* ol = outLo + (size_t)t * D_MODEL;
        oh[tid] = h0; oh[tid + 256] = h1;
        ol[tid] = l0; ol[tid + 256] = l1;
    }
    if (outb) {
        unsigned short* ob = outb + (size_t)t * D_MODEL;
        ob[tid] = f2bf(o0); ob[tid + 256] = f2bf(o1);
    }
    if (xcopy) {
        float* xc = xcopy + (size_t)t * D_MODEL;
        xc[tid] = v0; xc[tid + 256] = v1;
    }
}

// ------- Merged proj-weight transpose-split: z selects wq/wk/wv/wo (all 512x512) -------
__global__ __launch_bounds__(256) void tconv_split_proj(
    const float* __restrict__ wqp, const float* __restrict__ wkp,
    const float* __restrict__ wvp, const float* __restrict__ wop,
    unsigned short* __restrict__ qkvHi, unsigned short* __restrict__ qkvLo,
    unsigned short* __restrict__ oHi, unsigned short* __restrict__ oLo)
{
    __shared__ float Ts[32][33];
    const int tid = threadIdx.x;
    const int z = blockIdx.z;
    const float* in = (z == 0) ? wqp : (z == 1) ? wkp : (z == 2) ? wvp : wop;
    unsigned short* outHi = (z < 3) ? qkvHi + (size_t)z * 512 * 512 : oHi;
    unsigned short* outLo = (z < 3) ? qkvLo + (size_t)z * 512 * 512 : oLo;
    const int k0 = blockIdx.y * 32, n0 = blockIdx.x * 32;
    int r = tid >> 3, c = (tid & 7) * 4;
    float4 v = *(const float4*)&in[(size_t)(k0 + r) * D_MODEL + n0 + c];
    Ts[r][c] = v.x; Ts[r][c + 1] = v.y; Ts[r][c + 2] = v.z; Ts[r][c + 3] = v.w;
    __syncthreads();
    int n = tid >> 3, kk = (tid & 7) * 4;
    ushort4 h4, l4;
    split1(Ts[kk][n],     h4.x, l4.x); split1(Ts[kk + 1][n], h4.y, l4.y);
    split1(Ts[kk + 2][n], h4.z, l4.z); split1(Ts[kk + 3][n], h4.w, l4.w);
    size_t o = (size_t)(n0 + n) * D_MODEL + k0 + kk;
    *(ushort4*)&outHi[o] = h4;
    *(ushort4*)&outLo[o] = l4;
}

// ------- Merged L1 MoE chunk conv: z<8 -> w1 expert z, z>=8 -> w2 expert z-8 -------
__global__ __launch_bounds__(256) void tconv_split_moe(
    const float* __restrict__ w1c, const float* __restrict__ w2c,
    unsigned short* __restrict__ w1Hi, unsigned short* __restrict__ w1Lo,
    unsigned short* __restrict__ w2Hi, unsigned short* __restrict__ w2Lo)
{
    __shared__ float Ts[32][33];
    const int tid = threadIdx.x;
    const int z = blockIdx.z, e = z & 7, which = z >> 3;
    const float* in; int inLd;
    unsigned short *outHi, *outLo;
    if (which == 0) {
        in = w1c + (size_t)e * D_MODEL * DH_FF; inLd = DH_FF;
        outHi = w1Hi + (size_t)e * 512 * 512; outLo = w1Lo + (size_t)e * 512 * 512;
    } else {
        in = w2c + (size_t)e * DH_FF * D_MODEL; inLd = D_MODEL;
        outHi = w2Hi + (size_t)e * 512 * 512; outLo = w2Lo + (size_t)e * 512 * 512;
    }
    const int k0 = blockIdx.y * 32, n0 = blockIdx.x * 32;
    int r = tid >> 3, c = (tid & 7) * 4;
    float4 v = *(const float4*)&in[(size_t)(k0 + r) * inLd + n0 + c];
    Ts[r][c] = v.x; Ts[r][c + 1] = v.y; Ts[r][c + 2] = v.z; Ts[r][c + 3] = v.w;
    __syncthreads();
    int n = tid >> 3, kk = (tid & 7) * 4;
    ushort4 h4, l4;
    split1(Ts[kk][n],     h4.x, l4.x); split1(Ts[kk + 1][n], h4.y, l4.y);
    split1(Ts[kk + 2][n], h4.z, l4.z); split1(Ts[kk + 3][n], h4.w, l4.w);
    size_t o = (size_t)(n0 + n) * 512 + k0 + kk;
    *(ushort4*)&outHi[o] = h4;
    *(ushort4*)&outLo[o] = l4;
}

// ------- Merged L2 MoE chunk conv (bf16): z<8 -> w1 expert z, z>=8 -> w2 expert z-8 -------
// grid (32,16,16): which=0: n0=bx*32 (N=1024), k0=by*32 (K=512)
//                  which=1: k0=bx*32 (K=1024), n0=by*32 (N=512)
__global__ __launch_bounds__(256) void tconv_moe_bf(
    const float* __restrict__ w1c, const float* __restrict__ w2c,
    unsigned short* __restrict__ w1T, unsigned short* __restrict__ w2T)
{
    __shared__ float Ts[32][33];
    const int tid = threadIdx.x;
    const int z = blockIdx.z, e = z & 7, which = z >> 3;
    const float* in; int inLd, k0, n0, outLd;
    unsigned short* out;
    if (which == 0) {
        in = w1c + (size_t)e * D_MODEL * DH_FF; inLd = DH_FF;
        out = w1T + (size_t)e * 1024 * D_MODEL; outLd = D_MODEL;
        n0 = blockIdx.x * 32; k0 = blockIdx.y * 32;
    } else {
        in = w2c + (size_t)e * DH_FF * D_MODEL; inLd = D_MODEL;
        out = w2T + (size_t)e * D_MODEL * 1024; outLd = 1024;
        k0 = blockIdx.x * 32; n0 = blockIdx.y * 32;
    }
    int r = tid >> 3, c = (tid & 7) * 4;
    float4 v = *(const float4*)&in[(size_t)(k0 + r) * inLd + n0 + c];
    Ts[r][c] = v.x; Ts[r][c + 1] = v.y; Ts[r][c + 2] = v.z; Ts[r][c + 3] = v.w;
    __syncthreads();
    int n = tid >> 3, kk = (tid & 7) * 4;
    ushort4 o;
    o.x = f2bf(Ts[kk][n]);     o.y = f2bf(Ts[kk + 1][n]);
    o.z = f2bf(Ts[kk + 2][n]); o.w = f2bf(Ts[kk + 3][n]);
    *(ushort4*)&out[(size_t)(n0 + n) * outLd + k0 + kk] = o;
}

// ================= one-stage fp16x3 MFMA GEMM, 64x64 tiles, K-step 32 =================
// A pre-split hi/lo [M][K] (MODE2: gathered rows); B pre-split hi/lo [N][K] K-contig.
// MODE 0: C fp32 = acc                 (qkv, ldc=1536)
// MODE 1: C fp32 = acc + bias + resid  (o proj)
// MODE 2: Chi/Clo = split(gelu(acc+bias_e)), A gathered via rowtok (MoE up)
// MODE 5: atomicAdd(C[tok], rowgate*(acc + beta?bias_e:0)), skip pads (MoE down)
template<int MODE>
__global__ __launch_bounds__(256) void gemm_pre(
    const unsigned short* __restrict__ Ahi, const unsigned short* __restrict__ Alo,
    int lda, int KLEN,
    const unsigned short* __restrict__ Bhi, const unsigned short* __restrict__ Blo,
    size_t BeStride,
    float* __restrict__ C, int ldc,
    const float* __restrict__ bias, int biasStride,
    const float* __restrict__ resid,
    const int* __restrict__ offs, const int* __restrict__ rowtok, int beta,
    unsigned short* __restrict__ Chi, unsigned short* __restrict__ Clo)
{
    __shared__ unsigned short As_hi[64][40], As_lo[64][40];
    __shared__ unsigned short Bs_hi[64][40], Bs_lo[64][40];
    __shared__ int rt[64];
    __shared__ float rg[64];
    const int tid = threadIdx.x;
    int bx, by;
    xcd_swizzle(bx, by);
    const int row0 = by * 64, col0 = bx * 64;
    int e = 0;
    if (MODE == 2 || MODE == 5) {
        #pragma unroll
        for (int i = 1; i < N_EXP; i++) if (offs[i] <= row0) e = i;
        if (tid < 64) rt[tid] = rowtok[row0 + tid];
        if (MODE == 5 && tid >= 64 && tid < 128) rg[tid - 64] = resid[row0 + tid - 64];
        __syncthreads();
    }
    const unsigned short* BeH = Bhi + (size_t)e * BeStride;
    const unsigned short* BeL = Blo + (size_t)e * BeStride;
    const int lane = tid & 63, w = tid >> 6;
    const int wrow = (w >> 1) * 32, wcol = (w & 1) * 32;
    const int m_ = lane & 15, q_ = lane >> 4;
    f32x4_t acc[2][2];
    #pragma unroll
    for (int i = 0; i < 2; i++)
        #pragma unroll
        for (int j = 0; j < 2; j++) acc[i][j] = (f32x4_t){0.f, 0.f, 0.f, 0.f};

    const int sr = tid >> 2, sc = (tid & 3) * 8;   // 64 rows x 32k: 1 uint4/thread/array
    size_t arow;
    bool azero = false;
    if (MODE == 2) {
        int t = rt[sr];
        azero = (t < 0);
        arow = (size_t)(azero ? 0 : t) * lda;
    } else {
        arow = (size_t)(row0 + sr) * lda;
    }
    const size_t brow = (size_t)(col0 + sr) * KLEN;

    for (int k0 = 0; k0 < KLEN; k0 += 32) {
        uint4 vh = azero ? make_uint4(0u, 0u, 0u, 0u) : *(const uint4*)&Ahi[arow + k0 + sc];
        uint4 vl = azero ? make_uint4(0u, 0u, 0u, 0u) : *(const uint4*)&Alo[arow + k0 + sc];
        *(uint4*)&As_hi[sr][sc] = vh;
        *(uint4*)&As_lo[sr][sc] = vl;
        *(uint4*)&Bs_hi[sr][sc] = *(const uint4*)&BeH[brow + k0 + sc];
        *(uint4*)&Bs_lo[sr][sc] = *(const uint4*)&BeL[brow + k0 + sc];
        __syncthreads();
        f16x8 ah[2], al[2], bh[2], bl[2];
        #pragma unroll
        for (int i = 0; i < 2; i++) {
            int r = wrow + 16 * i + m_;
            ah[i] = *(const f16x8*)&As_hi[r][q_ * 8];
            al[i] = *(const f16x8*)&As_lo[r][q_ * 8];
        }
        #pragma unroll
        for (int j = 0; j < 2; j++) {
            int r = wcol + 16 * j + m_;
            bh[j] = *(const f16x8*)&Bs_hi[r][q_ * 8];
            bl[j] = *(const f16x8*)&Bs_lo[r][q_ * 8];
        }
        #pragma unroll
        for (int i = 0; i < 2; i++)
            #pragma unroll
            for (int j = 0; j < 2; j++) {
                acc[i][j] = __builtin_amdgcn_mfma_f32_16x16x32_f16(ah[i], bl[j], acc[i][j], 0, 0, 0);
                acc[i][j] = __builtin_amdgcn_mfma_f32_16x16x32_f16(al[i], bh[j], acc[i][j], 0, 0, 0);
                acc[i][j] = __builtin_amdgcn_mfma_f32_16x16x32_f16(ah[i], bh[j], acc[i][j], 0, 0, 0);
            }
        __syncthreads();
    }
    // C/D layout: col = lane&15, row = (lane>>4)*4 + reg  [validated r4]
    #pragma unroll
    for (int i = 0; i < 2; i++) {
        #pragma unroll
        for (int j = 0; j < 2; j++) {
            #pragma unroll
            for (int r = 0; r < 4; r++) {
                int lr = wrow + 16 * i + q_ * 4 + r;
                int gr = row0 + lr;
                int gc = col0 + wcol + 16 * j + m_;
                float v = acc[i][j][r];
                if (MODE == 5) {
                    int t = rt[lr];
                    if (t >= 0) {
                        float add = beta ? bias[(size_t)e * biasStride + gc] : 0.0f;
                        atomicAdd(&C[(size_t)t * ldc + gc], rg[lr] * (v + add));
                    }
                } else if (MODE == 2) {
                    float g = gelu_exact(v + bias[(size_t)e * biasStride + gc]);
                    unsigned short gh, gl;
                    split1(g, gh, gl);
                    size_t idx = (size_t)gr * ldc + gc;
                    Chi[idx] = gh; Clo[idx] = gl;
                } else {
                    size_t idx = (size_t)gr * ldc + gc;
                    if (MODE == 1) C[idx] = v + bias[gc] + resid[idx];
                    else           C[idx] = v;
                }
            }
        }
    }
}

// ================= one-stage bf16 MFMA GEMM (L2 MoE), 64x64 tiles, K-step 64 =========
// MODE 2: C bf16 = gelu(acc+bias_e), A bf16 gathered via rowtok (MoE up)
// MODE 5: atomicAdd(Cout[tok], rowgate*(acc + beta?bias_e:0)), skip pads
template<int MODE>
__global__ __launch_bounds__(256) void gemm_pre_bt(
    const unsigned short* __restrict__ A, int lda, int KLEN,
    const unsigned short* __restrict__ Bt, size_t BeStride,
    unsigned short* __restrict__ C, int ldc,
    const float* __restrict__ biasBase, int biasStride,
    const int* __restrict__ offs, const int* __restrict__ rowtok,
    const float* __restrict__ rowgate, float* __restrict__ Cout, int beta)
{
    __shared__ unsigned short As[64][72];
    __shared__ unsigned short Bs[64][72];
    __shared__ int rt[64];
    __shared__ float rg[64];
    const int tid = threadIdx.x;
    int bx, by;
    xcd_swizzle(bx, by);
    const int row0 = by * 64, col0 = bx * 64;
    int e = 0;
    #pragma unroll
    for (int i = 1; i < N_EXP; i++) if (offs[i] <= row0) e = i;
    if (tid < 64) rt[tid] = rowtok[row0 + tid];
    if (MODE == 5 && tid >= 64 && tid < 128) rg[tid - 64] = rowgate[row0 + tid - 64];
    __syncthreads();
    const unsigned short* Be = Bt + (size_t)e * BeStride;
    const int lane = tid & 63, w = tid >> 6;
    const int wrow = (w >> 1) * 32, wcol = (w & 1) * 32;
    const int m_ = lane & 15, q_ = lane >> 4;
    f32x4_t acc[2][2];
    #pragma unroll
    for (int i = 0; i < 2; i++)
        #pragma unroll
        for (int j = 0; j < 2; j++) acc[i][j] = (f32x4_t){0.f, 0.f, 0.f, 0.f};

    const int sr = tid >> 3, sc = (tid & 7) * 8;   // 64 rows x 64k: 2 uint4/thread/array
    size_t arow0, arow1;
    bool az0 = false, az1 = false;
    {
        int r1 = sr + 32;
        if (MODE == 2) {
            int t0 = rt[sr], t1 = rt[r1];
            az0 = (t0 < 0); az1 = (t1 < 0);
            arow0 = (size_t)(az0 ? 0 : t0) * lda;
            arow1 = (size_t)(az1 ? 0 : t1) * lda;
        } else {
            arow0 = (size_t)(row0 + sr) * lda;
            arow1 = (size_t)(row0 + r1) * lda;
        }
    }
    const size_t brow0 = (size_t)(col0 + sr) * KLEN;
    const size_t brow1 = (size_t)(col0 + sr + 32) * KLEN;

    for (int k0 = 0; k0 < KLEN; k0 += 64) {
        uint4 a0 = az0 ? make_uint4(0u, 0u, 0u, 0u) : *(const uint4*)&A[arow0 + k0 + sc];
        uint4 a1 = az1 ? make_uint4(0u, 0u, 0u, 0u) : *(const uint4*)&A[arow1 + k0 + sc];
        *(uint4*)&As[sr][sc]      = a0;
        *(uint4*)&As[sr + 32][sc] = a1;
        *(uint4*)&Bs[sr][sc]      = *(const uint4*)&Be[brow0 + k0 + sc];
        *(uint4*)&Bs[sr + 32][sc] = *(const uint4*)&Be[brow1 + k0 + sc];
        __syncthreads();
        #pragma unroll
        for (int ks = 0; ks < 2; ks++) {
            bf16x8_t af[2], bfr[2];
            #pragma unroll
            for (int i = 0; i < 2; i++)
                af[i] = *(const bf16x8_t*)&As[wrow + 16 * i + m_][ks * 32 + q_ * 8];
            #pragma unroll
            for (int j = 0; j < 2; j++)
                bfr[j] = *(const bf16x8_t*)&Bs[wcol + 16 * j + m_][ks * 32 + q_ * 8];
            #pragma unroll
            for (int i = 0; i < 2; i++)
                #pragma unroll
                for (int j = 0; j < 2; j++)
                    acc[i][j] = __builtin_amdgcn_mfma_f32_16x16x32_bf16(
                        af[i], bfr[j], acc[i][j], 0, 0, 0);
        }
        __syncthreads();
    }
    #pragma unroll
    for (int i = 0; i < 2; i++) {
        #pragma unroll
        for (int j = 0; j < 2; j++) {
            #pragma unroll
            for (int r = 0; r < 4; r++) {
                int lr = wrow + 16 * i + q_ * 4 + r;
                int gr = row0 + lr;
                int gc = col0 + wcol + 16 * j + m_;
                float v = acc[i][j][r];
                if (MODE == 5) {
                    int t = rt[lr];
                    if (t >= 0) {
                        float add = beta ? biasBase[(size_t)e * biasStride + gc] : 0.0f;
                        atomicAdd(&Cout[(size_t)t * ldc + gc], rg[lr] * (v + add));
                    }
                } else {
                    C[(size_t)gr * ldc + gc] =
                        f2bf(gelu_exact(v + biasBase[(size_t)e * biasStride + gc]));
                }
            }
        }
    }
}

// ---------------- QKV prep: fp32 qkvb slab -> fp16 head-major Q (x0.125), K, V^T ----------------
__global__ __launch_bounds__(256) void qkv_prep(
    const float* __restrict__ qkvb, unsigned short* __restrict__ Qh,
    unsigned short* __restrict__ Kh, unsigned short* __restrict__ VTh)
{
    __shared__ float Ts[64][65];
    const int tid = threadIdx.x;
    const int t0 = blockIdx.x * 64, hh = blockIdx.y, b = blockIdx.z;
    const int bh = b * 8 + hh;
    const float* src = qkvb + ((size_t)(b * S_SEQ + t0)) * QKV_LD + hh * 64;
    #pragma unroll
    for (int i = 0; i < 4; i++) {
        int flat = tid + i * 256;
        int r = flat >> 4, c4 = (flat & 15) * 4;
        float4 qv = *(const float4*)&src[(size_t)r * QKV_LD + c4];
        float4 kv = *(const float4*)&src[(size_t)r * QKV_LD + 512 + c4];
        float4 vv = *(const float4*)&src[(size_t)r * QKV_LD + 1024 + c4];
        ushort4 qo, ko;
        qo.x = f2h(qv.x * 0.125f); qo.y = f2h(qv.y * 0.125f);
        qo.z = f2h(qv.z * 0.125f); qo.w = f2h(qv.w * 0.125f);
        ko.x = f2h(kv.x); ko.y = f2h(kv.y); ko.z = f2h(kv.z); ko.w = f2h(kv.w);
        size_t o = ((size_t)bh * S_SEQ + t0 + r) * 64 + c4;
        *(ushort4*)&Qh[o] = qo;
        *(ushort4*)&Kh[o] = ko;
        Ts[r][c4] = vv.x; Ts[r][c4 + 1] = vv.y; Ts[r][c4 + 2] = vv.z; Ts[r][c4 + 3] = vv.w;
    }
    __syncthreads();
    #pragma unroll
    for (int i = 0; i < 4; i++) {
        int flat = tid + i * 256;
        int d = flat >> 4, s4 = (flat & 15) * 4;
        ushort4 vo;
        vo.x = f2h(Ts[s4][d]);     vo.y = f2h(Ts[s4 + 1][d]);
        vo.z = f2h(Ts[s4 + 2][d]); vo.w = f2h(Ts[s4 + 3][d]);
        *(ushort4*)&VTh[((size_t)bh * 64 + d) * S_SEQ + t0 + s4] = vo;
    }
}

// ---------------- Flash attention, fp16 MFMA, KV-split x2; writes raw partials ----------------
// grid (32, 8, 4): blockIdx.x = (qblock<<1)|seg; seg covers KV [seg*512, seg*512+512)
// oP [seg][bh][s][64] fp32 unnormalized; mP/lP [seg][bh][s] fp32.
__global__ __launch_bounds__(256) void flash_attn_mfma(
    const unsigned short* __restrict__ Qh, const unsigned short* __restrict__ Kh,
    const unsigned short* __restrict__ VTh,
    float* __restrict__ oP, float* __restrict__ mP, float* __restrict__ lP)
{
    __shared__ unsigned short Ks[64 * 72];
    __shared__ unsigned short Vt[64 * 72];
    __shared__ unsigned short Ps[64 * 72];
    const int tid = threadIdx.x;
    const int lane = tid & 63, w = tid >> 6;
    const int m_ = lane & 15, q_ = lane >> 4;
    const int hh = blockIdx.y, b = blockIdx.z;
    const int bh = b * 8 + hh;
    const int q0 = (blockIdx.x >> 1) * 64;
    const int seg = blockIdx.x & 1;
    const size_t qbase = ((size_t)bh * S_SEQ + q0) * 64;
    const size_t kbase = (size_t)bh * S_SEQ * 64;
    const size_t vbase = (size_t)bh * 64 * S_SEQ;

    f16x8 qa[2];
    #pragma unroll
    for (int c = 0; c < 2; c++)
        qa[c] = *(const f16x8*)&Qh[qbase + (size_t)(w * 16 + m_) * 64 + c * 32 + q_ * 8];

    float m_run[4], l_run[4];
    f32x4_t acc[4];
    #pragma unroll
    for (int r = 0; r < 4; r++) { m_run[r] = -INFINITY; l_run[r] = 0.0f; }
    #pragma unroll
    for (int oj = 0; oj < 4; oj++) acc[oj] = (f32x4_t){0.f, 0.f, 0.f, 0.f};

    const int kvEnd = seg * 512 + 512;
    for (int kv0 = seg * 512; kv0 < kvEnd; kv0 += 64) {
        __syncthreads();
        #pragma unroll
        for (int i = 0; i < 2; i++) {
            int g = tid + i * 256;
            int r = g >> 3, c8 = (g & 7) * 8;
            *(uint4*)&Ks[r * 72 + c8] =
                *(const uint4*)&Kh[kbase + (size_t)(kv0 + r) * 64 + c8];
            *(uint4*)&Vt[r * 72 + c8] =
                *(const uint4*)&VTh[vbase + (size_t)r * S_SEQ + kv0 + c8];
        }
        __syncthreads();
        f32x4_t s[4];
        #pragma unroll
        for (int j = 0; j < 4; j++) s[j] = (f32x4_t){0.f, 0.f, 0.f, 0.f};
        #pragma unroll
        for (int c = 0; c < 2; c++)
            #pragma unroll
            for (int j = 0; j < 4; j++) {
                f16x8 kb = *(const f16x8*)&Ks[(j * 16 + m_) * 72 + c * 32 + q_ * 8];
                s[j] = __builtin_amdgcn_mfma_f32_16x16x32_f16(qa[c], kb, s[j], 0, 0, 0);
            }
        float alpha[4];
        #pragma unroll
        for (int r = 0; r < 4; r++) {
            float rm = fmaxf(fmaxf(s[0][r], s[1][r]), fmaxf(s[2][r], s[3][r]));
            #pragma unroll
            for (int mk = 1; mk < 16; mk <<= 1)
                rm = fmaxf(rm, __shfl_xor(rm, mk));
            float mn = fmaxf(m_run[r], rm);
            alpha[r] = __expf(m_run[r] - mn);
            m_run[r] = mn;
            float ps = 0.0f;
            #pragma unroll
            for (int j = 0; j < 4; j++) {
                float p = __expf(s[j][r] - mn);
                s[j][r] = p;
                ps += p;
            }
            #pragma unroll
            for (int mk = 1; mk < 16; mk <<= 1)
                ps += __shfl_xor(ps, mk);
            l_run[r] = l_run[r] * alpha[r] + ps;
        }
        #pragma unroll
        for (int oj = 0; oj < 4; oj++)
            #pragma unroll
            for (int r = 0; r < 4; r++)
                acc[oj][r] *= alpha[r];
        #pragma unroll
        for (int j = 0; j < 4; j++)
            #pragma unroll
            for (int r = 0; r < 4; r++)
                Ps[(w * 16 + q_ * 4 + r) * 72 + j * 16 + m_] = f2h(s[j][r]);
        __syncthreads();
        #pragma unroll
        for (int c = 0; c < 2; c++) {
            f16x8 pa = *(const f16x8*)&Ps[(w * 16 + m_) * 72 + c * 32 + q_ * 8];
            #pragma unroll
            for (int oj = 0; oj < 4; oj++) {
                f16x8 vb = *(const f16x8*)&Vt[(oj * 16 + m_) * 72 + c * 32 + q_ * 8];
                acc[oj] = __builtin_amdgcn_mfma_f32_16x16x32_f16(pa, vb, acc[oj], 0, 0, 0);
            }
        }
    }
    const size_t pbase = (((size_t)seg * 32 + bh) * S_SEQ + q0) * 64;
    #pragma unroll
    for (int r = 0; r < 4; r++) {
        int row = w * 16 + q_ * 4 + r;
        #pragma unroll
        for (int oj = 0; oj < 4; oj++)
            oP[pbase + (size_t)row * 64 + oj * 16 + m_] = acc[oj][r];
        if (m_ == 0) {
            size_t mi = ((size_t)seg * 32 + bh) * S_SEQ + q0 + row;
            mP[mi] = m_run[r];
            lP[mi] = l_run[r];
        }
    }
}

// ---------------- Combine the 2 KV segments: exact online-softmax merge ----------------
__global__ __launch_bounds__(256) void attn_combine(
    const float* __restrict__ oP, const float* __restrict__ mP,
    const float* __restrict__ lP,
    unsigned short* __restrict__ outHi, unsigned short* __restrict__ outLo)
{
    const int tid = threadIdx.x;
    const int hh = blockIdx.y, b = blockIdx.z;
    const int bh = b * 8 + hh;
    const int q0 = blockIdx.x * 64;
    const int r = tid >> 2, c0 = (tid & 3) * 16;
    const int s = q0 + r;
    const size_t segO = (size_t)32 * S_SEQ * 64;
    const size_t segM = (size_t)32 * S_SEQ;
    const size_t b0 = ((size_t)bh * S_SEQ + s) * 64 + c0;
    const size_t mi = (size_t)bh * S_SEQ + s;
    float m0 = mP[mi], m1 = mP[segM + mi];
    float l0 = lP[mi], l1 = lP[segM + mi];
    float mm = fmaxf(m0, m1);
    float e0 = __expf(m0 - mm), e1 = __expf(m1 - mm);
    float inv = 1.0f / (l0 * e0 + l1 * e1);
    e0 *= inv; e1 *= inv;
    const size_t obase = ((size_t)b * S_SEQ + s) * D_MODEL + hh * 64 + c0;
    #pragma unroll
    for (int q = 0; q < 4; q++) {
        float4 v0 = *(const float4*)&oP[b0 + 4 * q];
        float4 v1 = *(const float4*)&oP[segO + b0 + 4 * q];
        float o0 = v0.x * e0 + v1.x * e1;
        float o1 = v0.y * e0 + v1.y * e1;
        float o2 = v0.z * e0 + v1.z * e1;
        float o3 = v0.w * e0 + v1.w * e1;
        ushort4 h4, l4;
        split1(o0, h4.x, l4.x); split1(o1, h4.y, l4.y);
        split1(o2, h4.z, l4.z); split1(o3, h4.w, l4.w);
        *(ushort4*)&outHi[obase + 4 * q] = h4;
        *(ushort4*)&outLo[obase + 4 * q] = l4;
    }
}

// ---------------- Gate: 4 tokens/block, pure shuffle reduce, NO atomics ----------------
__global__ __launch_bounds__(256) void gate_kernel(
    const float* __restrict__ h, const float* __restrict__ gw,
    int* __restrict__ topi, float* __restrict__ gates)
{
    const int w = threadIdx.x >> 6, lane = threadIdx.x & 63;
    const int t = blockIdx.x * 4 + w;
    const float* hr = h + (size_t)t * D_MODEL;
    float acc[N_EXP] = {};
    for (int d = lane; d < D_MODEL; d += 64) {
        float xv = hr[d];
        const float4 g0 = *(const float4*)&gw[(size_t)d * N_EXP];
        const float4 g1 = *(const float4*)&gw[(size_t)d * N_EXP + 4];
        acc[0] += xv * g0.x; acc[1] += xv * g0.y;
        acc[2] += xv * g0.z; acc[3] += xv * g0.w;
        acc[4] += xv * g1.x; acc[5] += xv * g1.y;
        acc[6] += xv * g1.z; acc[7] += xv * g1.w;
    }
    #pragma unroll
    for (int mk = 1; mk < 64; mk <<= 1) {
        #pragma unroll
        for (int e = 0; e < N_EXP; e++) acc[e] += __shfl_xor(acc[e], mk);
    }
    if (lane == 0) {
        int e0 = 0; float v0 = acc[0];
        #pragma unroll
        for (int e = 1; e < N_EXP; e++) if (acc[e] > v0) { v0 = acc[e]; e0 = e; }
        int e1 = -1; float v1 = -INFINITY;
        #pragma unroll
        for (int e = 0; e < N_EXP; e++) if (e != e0 && acc[e] > v1) { v1 = acc[e]; e1 = e; }
        float g0 = 1.0f / (1.0f + __expf(v1 - v0));
        float g1 = 1.0f - g0;
        topi[2 * t] = e0; topi[2 * t + 1] = e1;
        gates[2 * t] = g0; gates[2 * t + 1] = g1;
    }
}

// ---------------- Route: single block, ballot-based histogram + scatter, NO atomics ----------------
__global__ __launch_bounds__(1024) void route_kernel(
    const int* __restrict__ topi, const float* __restrict__ gates,
    int* __restrict__ offs, int* __restrict__ rowtok, float* __restrict__ rowgate)
{
    __shared__ int wcnt[16][N_EXP];
    __shared__ int wbase[16][N_EXP];
    __shared__ int offs_s[N_EXP + 1];
    const int tid = threadIdx.x, w = tid >> 6, lane = tid & 63;
    const unsigned long long lt = (1ULL << lane) - 1ULL;

    int mye[8];
    int cnt[N_EXP] = {};
    #pragma unroll
    for (int r = 0; r < 8; r++) {
        int i = w * 512 + r * 64 + lane;
        int e = topi[i];
        mye[r] = e;
        #pragma unroll
        for (int e8 = 0; e8 < N_EXP; e8++) {
            unsigned long long m = __ballot(e == e8);
            cnt[e8] += (int)__popcll(m);
        }
    }
    if (lane == 0) {
        #pragma unroll
        for (int e8 = 0; e8 < N_EXP; e8++) wcnt[w][e8] = cnt[e8];
    }
    __syncthreads();
    if (tid == 0) {
        int off = 0;
        for (int e8 = 0; e8 < N_EXP; e8++) {
            offs_s[e8] = off;
            int c = 0;
            for (int ww = 0; ww < 16; ww++) c += wcnt[ww][e8];
            off += (c + 127) & ~127;
        }
        offs_s[N_EXP] = off;
        for (int e8 = 0; e8 <= N_EXP; e8++) offs[e8] = offs_s[e8];
    }
    __syncthreads();
    if (tid < 128) {
        int ww = tid >> 3, e8 = tid & 7;
        int bse = offs_s[e8];
        for (int w2 = 0; w2 < ww; w2++) bse += wcnt[w2][e8];
        wbase[ww][e8] = bse;
    }
    __syncthreads();
    int base[N_EXP];
    #pragma unroll
    for (int e8 = 0; e8 < N_EXP; e8++) base[e8] = wbase[w][e8];
    #pragma unroll
    for (int r = 0; r < 8; r++) {
        int i = w * 512 + r * 64 + lane;
        int e = mye[r];
        int pos = 0;
        #pragma unroll
        for (int e8 = 0; e8 < N_EXP; e8++) {
            unsigned long long m = __ballot(e == e8);
            if (e == e8) pos = base[e8] + (int)__popcll(m & lt);
            base[e8] += (int)__popcll(m);
        }
        rowtok[pos] = i >> 1;
        rowgate[pos] = gates[i];
    }
}

extern "C" void kernel_launch(void* const* d_in, const int* in_sizes, int n_in,
                              void* d_out, int out_size, void* d_ws, size_t ws_size,
                              hipStream_t stream)
{
    const float* x0    = (const float*)d_in[0];
    const float* ln1w  = (const float*)d_in[1];
    const float* ln1b  = (const float*)d_in[2];
    const float* wq    = (const float*)d_in[3];
    const float* wk    = (const float*)d_in[4];
    const float* wv    = (const float*)d_in[5];
    const float* wo    = (const float*)d_in[6];
    const float* bo    = (const float*)d_in[7];
    const float* ln2w  = (const float*)d_in[8];
    const float* ln2b  = (const float*)d_in[9];
    const float* gatew = (const float*)d_in[10];
    const float* w1    = (const float*)d_in[11];
    const float* b1    = (const float*)d_in[12];
    const float* w2    = (const float*)d_in[13];
    const float* b2    = (const float*)d_in[14];
    float* out = (float*)d_out;

    // ---- Time-phased workspace (peak ~46.3 MiB) ----
    // attn phase: Qh@0 Kh@4 | h_hi@8 h_lo@12 -> attn_hi@8 attn_lo@12
    //   qkvb@16(24, dead after qkv_prep) -> oPart@16(16.8) mPart@33 lPart@33.5 -> x1@16
    //   wqkvT@40(3, dead after qkv gemm) -> VTh@40(4) | woT@44(2) | ints@46
    // MoE phase: as R4/R6.
    char* ws = (char*)d_ws;
    const size_t MiB = 1 << 20;
    unsigned short* Qh    = (unsigned short*)(ws + 0);
    unsigned short* Kh    = (unsigned short*)(ws + 4 * MiB);
    unsigned short* h_hi  = (unsigned short*)(ws + 8 * MiB);
    unsigned short* h_lo  = (unsigned short*)(ws + 12 * MiB);
    unsigned short* attn_hi = (unsigned short*)(ws + 8 * MiB);
    unsigned short* attn_lo = (unsigned short*)(ws + 12 * MiB);
    float* qkvb = (float*)(ws + 16 * MiB);
    float* x1   = (float*)(ws + 16 * MiB);
    float* oPart = (float*)(ws + 16 * MiB);
    float* mPart = (float*)(ws + 33 * MiB);
    float* lPart = (float*)(ws + 33 * MiB + 512 * 1024);
    unsigned short* wqkvT_hi = (unsigned short*)(ws + 40 * MiB);
    unsigned short* wqkvT_lo = (unsigned short*)(ws + 40 * MiB + QKV_LD * D_MODEL * 2);
    unsigned short* VTh   = (unsigned short*)(ws + 40 * MiB);
    unsigned short* woT_hi = (unsigned short*)(ws + 44 * MiB);
    unsigned short* woT_lo = (unsigned short*)(ws + 44 * MiB + D_MODEL * D_MODEL * 2);
    unsigned short* h2_hi = (unsigned short*)(ws + 0);
    unsigned short* h2_lo = (unsigned short*)(ws + 4 * MiB);
    unsigned short* h2b   = (unsigned short*)(ws + 0);
    float* h2 = (float*)(ws + 8 * MiB);
    unsigned short* w1T_hi = (unsigned short*)(ws + 8 * MiB);
    unsigned short* w1T_lo = (unsigned short*)(ws + 12 * MiB);
    unsigned short* w2T_hi = (unsigned short*)(ws + 16 * MiB);
    unsigned short* w2T_lo = (unsigned short*)(ws + 20 * MiB);
    unsigned short* hmid_hi = (unsigned short*)(ws + 24 * MiB);
    unsigned short* hmid_lo = (unsigned short*)(ws + 33 * MiB);
    unsigned short* w1T_bf  = (unsigned short*)(ws + 8 * MiB);
    unsigned short* w2T_bf  = (unsigned short*)(ws + 16 * MiB);
    unsigned short* hmidb   = (unsigned short*)(ws + 24 * MiB);
    size_t oI = 46 * MiB;
    int*   topi    = (int*)(ws + oI);
    float* gates   = (float*)(ws + oI + 2 * T_TOK * 4);
    int*   rowtok  = (int*)(ws + oI + 4 * T_TOK * 4);
    float* rowgate = (float*)(ws + oI + 4 * T_TOK * 4 + CAP * 4);
    int*   offs    = (int*)(ws + oI + 4 * T_TOK * 4 + 2 * CAP * 4);
    float* x2 = out;   // inter-layer residual lives in d_out

    const dim3 gWproj(16, 16, 4);
    const dim3 gWmoe(16, 16, 16);
    const dim3 gWmoe2(32, 16, 16);
    const dim3 gQKV(QKV_LD / 64, T_TOK / 64);    // 24 x 64 = 1536
    const dim3 gO(D_MODEL / 64, T_TOK / 64);     // 8 x 64 = 512
    const dim3 gUp1(8, CAP / 64);                // 1152 (CHUNK=512)
    const dim3 gDn1(D_MODEL / 64, CAP / 64);     // 1152
    const dim3 gUp2(16, CAP / 64);               // 2304 (CHUNK=1024)
    const dim3 gDn2(D_MODEL / 64, CAP / 64);     // 1152
    const dim3 gAttnF(2 * S_SEQ / 64, 8, 4);     // 32 x 8 x 4 = 1024 (KV-split x2)
    const dim3 gAttnC(S_SEQ / 64, 8, 4);         // combine + prep
    const dim3 gPrep(S_SEQ / 64, 8, 4);

    for (int l = 0; l < 2; l++) {
        const float* xin = (l == 0) ? x0 : x2;
        float* xout = (l == 1) ? out : x2;
        const float* wq_l = wq + (size_t)l * D_MODEL * D_MODEL;
        const float* wk_l = wk + (size_t)l * D_MODEL * D_MODEL;
        const float* wv_l = wv + (size_t)l * D_MODEL * D_MODEL;
        const float* wo_l = wo + (size_t)l * D_MODEL * D_MODEL;
        const float* w1_l = w1 + (size_t)l * N_EXP * D_MODEL * DH_FF;
        const float* w2_l = w2 + (size_t)l * N_EXP * DH_FF * D_MODEL;
        const float* b1_l = b1 + (size_t)l * N_EXP * DH_FF;
        const float* b2_l = b2 + (size_t)l * N_EXP * D_MODEL;

        ln_kernel<<<T_TOK, 256, 0, stream>>>(xin, ln1w + (size_t)l * D_MODEL,
                                             ln1b + (size_t)l * D_MODEL,
                                             nullptr, h_hi, h_lo, nullptr, nullptr);
        tconv_split_proj<<<gWproj, 256, 0, stream>>>(wq_l, wk_l, wv_l, wo_l,
                                                     wqkvT_hi, wqkvT_lo, woT_hi, woT_lo);
        gemm_pre<0><<<gQKV, 256, 0, stream>>>(h_hi, h_lo, D_MODEL, D_MODEL,
                                              wqkvT_hi, wqkvT_lo, 0,
                                              qkvb, QKV_LD, nullptr, 0, nullptr,
                                              nullptr, nullptr, 0, nullptr, nullptr);
        qkv_prep<<<gPrep, 256, 0, stream>>>(qkvb, Qh, Kh, VTh);
        flash_attn_mfma<<<gAttnF, 256, 0, stream>>>(Qh, Kh, VTh, oPart, mPart, lPart);
        attn_combine<<<gAttnC, 256, 0, stream>>>(oPart, mPart, lPart, attn_hi, attn_lo);
        gemm_pre<1><<<gO, 256, 0, stream>>>(attn_hi, attn_lo, D_MODEL, D_MODEL,
                                            woT_hi, woT_lo, 0,
                                            x1, D_MODEL, bo + (size_t)l * D_MODEL, 0,
                                            xin, nullptr, nullptr, 0, nullptr, nullptr);
        ln_kernel<<<T_TOK, 256, 0, stream>>>(x1, ln2w + (size_t)l * D_MODEL,
                                             ln2b + (size_t)l * D_MODEL, h2,
                                             (l == 0) ? h2_hi : nullptr,
                                             (l == 0) ? h2_lo : nullptr,
                                             (l == 1) ? h2b : nullptr, xout);

        hipMemsetAsync(rowtok, 0xFF, CAP * 4, stream);
        gate_kernel<<<T_TOK / 4, 256, 0, stream>>>(h2, gatew + (size_t)l * D_MODEL * N_EXP,
                                                   topi, gates);
        route_kernel<<<1, 1024, 0, stream>>>(topi, gates, offs, rowtok, rowgate);

        if (l == 0) {
            for (int c = 0; c < 4; c++) {
                tconv_split_moe<<<gWmoe, 256, 0, stream>>>(
                    w1_l + (size_t)c * 512, w2_l + (size_t)c * 512 * D_MODEL,
                    w1T_hi, w1T_lo, w2T_hi, w2T_lo);
                gemm_pre<2><<<gUp1, 256, 0, stream>>>(h2_hi, h2_lo, D_MODEL, D_MODEL,
                                                      w1T_hi, w1T_lo, (size_t)512 * D_MODEL,
                                                      nullptr, 512,
                                                      b1_l + (size_t)c * 512, DH_FF,
                                                      nullptr, offs, rowtok, 0,
                                                      hmid_hi, hmid_lo);
                gemm_pre<5><<<gDn1, 256, 0, stream>>>(hmid_hi, hmid_lo, 512, 512,
                                                      w2T_hi, w2T_lo, (size_t)D_MODEL * 512,
                                                      xout, D_MODEL, b2_l, D_MODEL,
                                                      rowgate, offs, rowtok,
                                                      (c == 0) ? 1 : 0, nullptr, nullptr);
            }
        } else {
            for (int c = 0; c < 2; c++) {
                tconv_moe_bf<<<gWmoe2, 256, 0, stream>>>(
                    w1_l + (size_t)c * 1024, w2_l + (size_t)c * 1024 * D_MODEL,
                    w1T_bf, w2T_bf);
                gemm_pre_bt<2><<<gUp2, 256, 0, stream>>>(h2b, D_MODEL, D_MODEL,
                                                         w1T_bf, (size_t)1024 * D_MODEL,
                                                         hmidb, 1024,
                                                         b1_l + (size_t)c * 1024, DH_FF,
                                                         offs, rowtok, nullptr, nullptr, 0);
                gemm_pre_bt<5><<<gDn2, 256, 0, stream>>>(hmidb, 1024, 1024,
                                                         w2T_bf, (size_t)D_MODEL * 1024,
                                                         nullptr, D_MODEL, b2_l, D_MODEL,
                                                         offs, rowtok, rowgate, xout,
                                                         (c == 0) ? 1 : 0);
            }
        }
    }
}